// Round 5
// baseline (42176.804 us; speedup 1.0000x reference)
//
#include <hip/hip_runtime.h>
#include <stdint.h>

// ---------------- problem sizes ----------------
constexpr int kB = 64, kT = 512, kD = 512, kH = 1024, kO = 256;

// ---------------- grid config ----------------
constexpr int NBLK = 256;   // block Z owns units 4Z..4Z+3 of L1 AND L2, all 64 batches
constexpr int NTHR = 192;   // wave 0: L1(Wh1)  wave 1: W12(+LIF2+combine)  wave 2: Wh2

// ---------------- ws layout (bytes) ----------------
constexpr size_t OFF_U2   = 0;                                   // U2[t][b][u] f32 (128 MB) = x@W_in.T + b_in
constexpr size_t OFF_WINT = OFF_U2   + (size_t)kT*kB*kH*4;       // WinT[k][u] f32 (2 MB); dead after uproj ->
                                                                 //   reused for flags + spike-row rings
constexpr size_t OFF_WS1  = OFF_WINT + (size_t)kD*kH*4;          // Wh1 sliced [u/4][j][4] (4 MB)
constexpr size_t OFF_WS2  = OFF_WS1  + (size_t)kH*kH*4;          // W12 sliced
constexpr size_t OFF_WS3  = OFF_WS2  + (size_t)kH*kH*4;          // Wh2 sliced
constexpr size_t OFF_CNT  = OFF_WS3  + (size_t)kH*kH*4;          // cnt[b][u] u32 (256 KB)

// dataflow arena (inside dead WinT region, memset to 0 after uproj):
//   rdy1[256] int @ +0     : block Z stores p+1 after publishing s1 gen p (release)
//   rdy2[256] int @ +1024  : block Z stores p   after publishing s2 gen p-1 (release)
//   ack [256] int @ +2048  : block Z stores p+1 after ALL its step-p reads done (release)
//   s1ring[4][1024] u64 @ +4096   (gen g in slot g&3)
//   s2ring[4][1024] u64 @ +36864
constexpr size_t ARN_RDY1 = 0;
constexpr size_t ARN_RDY2 = 1024;
constexpr size_t ARN_ACK  = 2048;
constexpr size_t ARN_S1R  = 4096;
constexpr size_t ARN_S2R  = ARN_S1R + 4 * kH * 8;
constexpr size_t ARN_BYTES = ARN_S2R + 4 * kH * 8;   // 69632 B

// cross-block data via agent-scope atomics (per-XCD L2s not coherent)
__device__ __forceinline__ uint64_t ld64(const uint64_t* p) {
  return __hip_atomic_load(p, __ATOMIC_RELAXED, __HIP_MEMORY_SCOPE_AGENT);
}
__device__ __forceinline__ void st64(uint64_t* p, uint64_t v) {
  __hip_atomic_store(p, v, __ATOMIC_RELAXED, __HIP_MEMORY_SCOPE_AGENT);
}

// wave-parallel wait: all f[0..255] >= thr. Lane L checks words 4L..4L+3; acquire
// loads pair with each producer's release store (wave-level: the successful pass's
// waitcnt+inv orders all subsequent row loads after all 256 flag observations).
// thr<=0 is trivially true (flags start at 0, monotonic nonneg).
__device__ __forceinline__ void waitarr(const int* f, int lane, int thr) {
  if (thr <= 0) return;
  const int i0 = lane * 4;
  for (;;) {
    int a = __hip_atomic_load(f + i0 + 0, __ATOMIC_ACQUIRE, __HIP_MEMORY_SCOPE_AGENT);
    int b = __hip_atomic_load(f + i0 + 1, __ATOMIC_ACQUIRE, __HIP_MEMORY_SCOPE_AGENT);
    int c = __hip_atomic_load(f + i0 + 2, __ATOMIC_ACQUIRE, __HIP_MEMORY_SCOPE_AGENT);
    int d = __hip_atomic_load(f + i0 + 3, __ATOMIC_ACQUIRE, __HIP_MEMORY_SCOPE_AGENT);
    bool ok = (a >= thr) && (b >= thr) && (c >= thr) && (d >= thr);
    if (__all(ok ? 1 : 0)) break;
    __builtin_amdgcn_s_sleep(1);
  }
}
__device__ __forceinline__ void postflag(int* f, int v) {
  __hip_atomic_store(f, v, __ATOMIC_RELEASE, __HIP_MEMORY_SCOPE_AGENT);
}

// ---------- transpose f32 in[R][C] -> out[C][R] (for WinT) ----------
__global__ void transpose_k(const float* __restrict__ in, float* __restrict__ out,
                            int R, int C) {
  __shared__ float tile[32][33];
  int c0 = blockIdx.x * 32, r0 = blockIdx.y * 32;
  int tx = threadIdx.x, ty = threadIdx.y;           // (32,8)
  for (int k = 0; k < 32; k += 8)
    tile[ty + k][tx] = in[(size_t)(r0 + ty + k) * C + c0 + tx];
  __syncthreads();
  for (int k = 0; k < 32; k += 8)
    out[(size_t)(c0 + ty + k) * R + r0 + tx] = tile[tx][ty + k];
}

// ---------- W[1024][1024] -> sliced S[(u>>2)*1024 + j][4] with S[..][q] = W[4Z+q][j] ----------
__global__ void wtr_sl(const float* __restrict__ in, float* __restrict__ out) {
  int u = blockIdx.x;
  int j = blockIdx.y * 256 + threadIdx.x;
  float v = in[(size_t)u * kH + j];
  out[((size_t)(u >> 2) * kH + j) * 4 + (u & 3)] = v;
}

// ---------- U2[t][b][u] = x@W_in.T + b_in  (bit-exact-proven kernel, unchanged) ----------
__global__ __launch_bounds__(256) void uproj(const float* __restrict__ x,
                                             const float* __restrict__ WinT,
                                             const float* __restrict__ b_in,
                                             float* __restrict__ U2) {
  const int t    = blockIdx.x;                 // 512
  const int uc   = blockIdx.y;                 // 16
  const int lane = threadIdx.x & 63;
  const int wvu  = __builtin_amdgcn_readfirstlane(threadIdx.x >> 6);  // 0..3
  const int u    = uc * 64 + lane;
  const int b0   = wvu * 16;
  float acc[16];
  #pragma unroll
  for (int i = 0; i < 16; ++i) acc[i] = 0.0f;
  for (int k = 0; k < kD; k += 4) {
    float w0 = WinT[(size_t)(k + 0) * kH + u];
    float w1 = WinT[(size_t)(k + 1) * kH + u];
    float w2 = WinT[(size_t)(k + 2) * kH + u];
    float w3 = WinT[(size_t)(k + 3) * kH + u];
    #pragma unroll
    for (int bb = 0; bb < 16; ++bb) {
      const float4 xv = *(const float4*)(x + ((size_t)(b0 + bb) * kT + t) * kD + k);
      acc[bb] = __fmaf_rn(xv.x, w0, acc[bb]);   // ascending k, single chain: np-exact
      acc[bb] = __fmaf_rn(xv.y, w1, acc[bb]);
      acc[bb] = __fmaf_rn(xv.z, w2, acc[bb]);
      acc[bb] = __fmaf_rn(xv.w, w3, acc[bb]);
    }
  }
  float bi = b_in[u];
  #pragma unroll
  for (int bb = 0; bb < 16; ++bb)
    U2[((size_t)t * kB + (b0 + bb)) * kH + u] = __fadd_rn(acc[bb], bi);
}

// sequential-j chain over 1024 spike-gated weights from LDS; bit-exact vs R4:
// fma(w, sf, B) with sf in {0,1} == fadd(B, bit?w:0); B starts +0 and RN cancellation
// yields +0, so B is never -0 and the ±0 corners coincide.
// R5 ping-pong double-buffer kept (neutral; wlds needs 8 float4 tail pad).
__device__ __forceinline__ void chain1024(const uint64_t* rows, const float4* wlds,
                                          int lane, float acc[4], float fone) {
  float4 bufA[8], bufB[8];                              // static-indexed only (no scratch)
  uint64_t cur = ld64(&rows[lane]);                     // group 0: lane L holds word j=L
  #pragma unroll
  for (int i = 0; i < 8; ++i) bufA[i] = wlds[i];        // preload j=0..7
  #pragma unroll 1
  for (int g = 0; g < 16; ++g) {
    uint64_t nxt = (g < 15) ? ld64(&rows[(g + 1) * 64 + lane]) : 0ull;  // prefetch next group
    uint32_t lo = (uint32_t)cur, hi = (uint32_t)(cur >> 32);
    const float4* wg = wlds + g * 64;
    #pragma unroll
    for (int sb = 0; sb < 8; ++sb) {                    // 8 sub-blocks of 8 jj
      #pragma unroll
      for (int i = 0; i < 8; ++i) {
        float4 w = wg[(sb + 1) * 8 + i];                // sb=7,g=15 -> pad region (unused)
        if (sb & 1) bufA[i] = w; else bufB[i] = w;
      }
      #pragma unroll
      for (int i = 0; i < 8; ++i) {
        const int jj = sb * 8 + i;
        uint32_t rlo = (uint32_t)__builtin_amdgcn_readlane((int)lo, jj);  // word for j=g*64+jj
        uint32_t rhi = (uint32_t)__builtin_amdgcn_readlane((int)hi, jj);
        uint64_t rw  = ((uint64_t)rhi << 32) | rlo;     // uniform -> SGPR pair
        float sf;
        asm("v_cndmask_b32 %0, 0, %1, %2" : "=v"(sf) : "v"(fone), "s"(rw));  // sf = bit(lane)
        float4 w4 = (sb & 1) ? bufB[i] : bufA[i];       // compile-time select
        acc[0] = __fmaf_rn(w4.x, sf, acc[0]);
        acc[1] = __fmaf_rn(w4.y, sf, acc[1]);
        acc[2] = __fmaf_rn(w4.z, sf, acc[2]);
        acc[3] = __fmaf_rn(w4.w, sf, acc[3]);
      }
    }
    cur = nxt;
  }
}

// ---------- persistent SNN, R9: dataflow sync, NO grid barrier ----------
// s1 gen g lives in s1ring slot g&3 (same for s2). Depth-4 ring => blocks may
// drift up to 3 steps. Guards (all thresholds verified at the init corners):
//   reader of s1 gen p-1 (step p):        all rdy1 >= p
//   reader of s2 gen p-2 (step p, wv2):   all rdy2 >= p-1
//   writer of s1 gen p / s2 gen p-1:      all ack  >= p-2   (gen p-4 readers, who
//     read at step p-3 and acked p-2, are done; ring depth 4 => no other aliasing)
__global__ __launch_bounds__(NTHR, 1) void snn6(
    const float* __restrict__ U2,
    const float* __restrict__ Wh1S, const float* __restrict__ W12S,
    const float* __restrict__ Wh2S,
    const float* __restrict__ b_h1, const float* __restrict__ b_12,
    const float* __restrict__ b_h2,
    uint64_t* s1ring, uint64_t* s2ring, uint32_t* cnt2,
    int* rdy1, int* rdy2, int* ackf)
{
  __shared__ float4 ldsW[3][kH + 8];   // ~48.4 KB: per-role 4-unit weight slice + prefetch pad
  __shared__ float  xch[4][64];        // B2 exchange (Wh2 wave -> W12 wave)

  const int tid  = threadIdx.x;
  const int lane = tid & 63;                                          // batch
  const int wv   = __builtin_amdgcn_readfirstlane(tid >> 6);          // role 0/1/2
  const int Z    = blockIdx.x;
  const float fone = 1.0f;

  // ---- one-time: preload this role's 16 KB weight slice into LDS (coalesced).
  // Each wave reads only its own slice later -> wave-local, no barrier needed.
  {
    const float* Wsrc = (wv == 0) ? Wh1S : (wv == 1) ? W12S : Wh2S;
    const float4* gs = (const float4*)Wsrc + (size_t)Z * kH;
    #pragma unroll
    for (int i = 0; i < 16; ++i) {
      int idx = i * 64 + lane;
      ldsW[wv][idx] = gs[idx];
    }
  }

  float bA[4];           // role bias: b_h1 / b_12 / b_h2 for units 4Z..4Z+3
  float bh2v[4];         // W12 wave also needs b_h2 for the combine
  float v[4];            // membrane state per (unit q, batch lane)
  float B1[4];           // W12 wave: stashed partial across syncthreads
  uint32_t cnt[4] = {0, 0, 0, 0};
  #pragma unroll
  for (int q = 0; q < 4; ++q) {
    v[q] = 0.0f;
    B1[q] = 0.0f;
    bA[q]   = (wv == 0) ? b_h1[4 * Z + q] : (wv == 1) ? b_12[4 * Z + q] : b_h2[4 * Z + q];
    bh2v[q] = b_h2[4 * Z + q];
  }

  for (int p = 0; p <= kT; ++p) {
    const uint64_t* r1g = s1ring + (size_t)((p + 3) & 3) * kH;   // s1 gen p-1
    uint64_t*       w1g = s1ring + (size_t)(p & 3)       * kH;   // s1 gen p
    const uint64_t* r2g = s2ring + (size_t)((p + 2) & 3) * kH;   // s2 gen p-2
    uint64_t*       w2g = s2ring + (size_t)((p + 3) & 3) * kH;   // s2 gen p-1

    if (wv == 0) {
      if (p < kT) {   // L1 step t=p
        waitarr(rdy1, lane, p);        // s1 gen p-1 published by all
        waitarr(ackf, lane, p - 2);    // slot p&3's old readers done
        // prefetch A early (no deps on the chain): latency hidden by chain1024
        float4 A4 = *(const float4*)(U2 + ((size_t)p * kB + lane) * kH + 4 * Z);
        float acc[4] = {0.f, 0.f, 0.f, 0.f};
        chain1024(r1g, ldsW[0], lane, acc, fone);                // s1(p-1)@W_h1.T
        float A[4] = {A4.x, A4.y, A4.z, A4.w};
        #pragma unroll
        for (int q = 0; q < 4; ++q) {
          float h = __fadd_rn(__fadd_rn(A[q], acc[q]), bA[q]);   // ((x@W+b_in)+rec)+b_h1
          v[q] = __fadd_rn(__fmul_rn(0.9f, v[q]), h);
          bool s = (v[q] >= 1.0f);
          if (s) v[q] = __fsub_rn(v[q], 1.0f);
          uint64_t m = __ballot(s);                              // bits = batches
          if (lane == 0) st64(&w1g[4 * Z + q], m);
        }
        if (lane == 0) postflag(&rdy1[Z], p + 1);                // release: rows -> flag
      }
    } else if (wv == 1) {
      if (p >= 1) {   // L2 step t=p-1, part 1: B1 = s1(p-1)@W_12.T
        waitarr(rdy1, lane, p);
        waitarr(ackf, lane, p - 2);    // for this step's w2g write (slot (p-1)&3)
        float acc[4] = {0.f, 0.f, 0.f, 0.f};
        chain1024(r1g, ldsW[1], lane, acc, fone);
        #pragma unroll
        for (int q = 0; q < 4; ++q) B1[q] = acc[q];
      }
    } else {
      if (p >= 1) {   // L2 part 2: B2 = s2(p-2)@W_h2.T
        waitarr(rdy2, lane, p - 1);
        float acc[4] = {0.f, 0.f, 0.f, 0.f};
        chain1024(r2g, ldsW[2], lane, acc, fone);
        #pragma unroll
        for (int q = 0; q < 4; ++q) xch[q][lane] = acc[q];
      }
    }
    __syncthreads();   // all reads of gens p-1/p-2 complete block-wide; xch visible
    if (wv == 2 && lane == 0) postflag(&ackf[Z], p + 1);
    if (wv == 1 && p >= 1) {   // combine + LIF2 + publish (exact op order)
      #pragma unroll
      for (int q = 0; q < 4; ++q) {
        float C = __fadd_rn(B1[q], bA[q]);                        // B1 + b_12
        float h = __fadd_rn(__fadd_rn(C, xch[q][lane]), bh2v[q]); // (C+B2)+b_h2
        v[q] = __fadd_rn(__fmul_rn(0.9f, v[q]), h);
        bool s = (v[q] >= 1.0f);
        if (s) { v[q] = __fsub_rn(v[q], 1.0f); cnt[q]++; }
        uint64_t m = __ballot(s);
        if (lane == 0) st64(&w2g[4 * Z + q], m);
      }
      if (lane == 0) postflag(&rdy2[Z], p);                       // release: rows -> flag
    }
    __syncthreads();   // protect xch (next step's wv2 write) and LDS reuse
  }

  if (wv == 1) {
    #pragma unroll
    for (int q = 0; q < 4; ++q) cnt2[(size_t)lane * kH + 4 * Z + q] = cnt[q];
  }
}

// ---------- exact f64 readout: out[b][o] = sum_j cnt[b][j]*W_out[o][j] + 512*b_out[o] ----------
__global__ void readout(const uint32_t* __restrict__ cnt2, const float* __restrict__ W_out,
                        const float* __restrict__ b_out, float* __restrict__ out) {
  const int b = blockIdx.x;    // 64
  const int o = threadIdx.x;   // 256
  double po = 512.0 * (double)b_out[o];
  for (int j = 0; j < kH; j += 4) {
    uint4  c4 = *(const uint4*)(cnt2 + (size_t)b * kH + j);
    float4 w4 = *(const float4*)(W_out + (size_t)o * kH + j);
    po = fma((double)c4.x, (double)w4.x, po);
    po = fma((double)c4.y, (double)w4.y, po);
    po = fma((double)c4.z, (double)w4.z, po);
    po = fma((double)c4.w, (double)w4.w, po);
  }
  out[(size_t)b * kO + o] = (float)po;
}

extern "C" void kernel_launch(void* const* d_in, const int* in_sizes, int n_in,
                              void* d_out, int out_size, void* d_ws, size_t ws_size,
                              hipStream_t stream) {
  (void)in_sizes; (void)n_in; (void)out_size; (void)ws_size;
  const float* x     = (const float*)d_in[0];
  const float* W_in  = (const float*)d_in[1];
  const float* pb_in = (const float*)d_in[2];
  const float* W_h1  = (const float*)d_in[3];
  const float* pb_h1 = (const float*)d_in[4];
  const float* W_12  = (const float*)d_in[5];
  const float* pb_12 = (const float*)d_in[6];
  const float* W_h2  = (const float*)d_in[7];
  const float* pb_h2 = (const float*)d_in[8];
  const float* W_out = (const float*)d_in[9];
  const float* pb_out= (const float*)d_in[10];
  float* out = (float*)d_out;

  char* ws = (char*)d_ws;
  float*    U2    = (float*)   (ws + OFF_U2);
  float*    WinT  = (float*)   (ws + OFF_WINT);
  float*    Wh1S  = (float*)   (ws + OFF_WS1);
  float*    W12S  = (float*)   (ws + OFF_WS2);
  float*    Wh2S  = (float*)   (ws + OFF_WS3);
  uint32_t* cnt2  = (uint32_t*)(ws + OFF_CNT);
  int*      rdy1  = (int*)     (ws + OFF_WINT + ARN_RDY1);
  int*      rdy2  = (int*)     (ws + OFF_WINT + ARN_RDY2);
  int*      ackf  = (int*)     (ws + OFF_WINT + ARN_ACK);
  uint64_t* s1r   = (uint64_t*)(ws + OFF_WINT + ARN_S1R);
  uint64_t* s2r   = (uint64_t*)(ws + OFF_WINT + ARN_S2R);

  hipLaunchKernelGGL(transpose_k, dim3(kD / 32, kH / 32), dim3(32, 8), 0, stream,
                     W_in, WinT, kH, kD);
  hipLaunchKernelGGL(wtr_sl, dim3(kH, 4), dim3(256), 0, stream, W_h1, Wh1S);
  hipLaunchKernelGGL(wtr_sl, dim3(kH, 4), dim3(256), 0, stream, W_12, W12S);
  hipLaunchKernelGGL(wtr_sl, dim3(kH, 4), dim3(256), 0, stream, W_h2, Wh2S);
  hipLaunchKernelGGL(uproj, dim3(kT, 16), dim3(256), 0, stream, x, WinT, pb_in, U2);
  // WinT is dead after uproj: zero flags + both spike-row rings (stream-ordered)
  hipMemsetAsync(ws + OFF_WINT, 0, ARN_BYTES, stream);

  void* args[] = {(void*)&U2, (void*)&Wh1S, (void*)&W12S, (void*)&Wh2S,
                  (void*)&pb_h1, (void*)&pb_12, (void*)&pb_h2,
                  (void*)&s1r, (void*)&s2r, (void*)&cnt2,
                  (void*)&rdy1, (void*)&rdy2, (void*)&ackf};
  hipLaunchCooperativeKernel((void*)snn6, dim3(NBLK), dim3(NTHR), args, 0, stream);

  hipLaunchKernelGGL(readout, dim3(kB), dim3(kO), 0, stream, cnt2, W_out, pb_out, out);
}

// Round 6
// 21209.592 us; speedup vs baseline: 1.9886x; 1.9886x over previous
//
#include <hip/hip_runtime.h>
#include <stdint.h>

// ---------------- problem sizes ----------------
constexpr int kB = 64, kT = 512, kD = 512, kH = 1024, kO = 256;

// ---------------- grid config ----------------
constexpr int NBLK = 256;   // block Z owns units 4Z..4Z+3 of L1 AND L2, all 64 batches
constexpr int NTHR = 192;   // wave 0: L1(Wh1)  wave 1: W12(+LIF2+combine)  wave 2: Wh2

// ---------------- ws layout (bytes) — total ~142.3 MB (== R4's proven footprint) ----------------
constexpr size_t OFF_U2   = 0;                                   // U2[t][b][u] f32 (128 MB) = x@W_in.T + b_in
constexpr size_t OFF_WINT = OFF_U2   + (size_t)kT*kB*kH*4;       // WinT[k][u] f32 (2 MB)
constexpr size_t OFF_WS1  = OFF_WINT + (size_t)kD*kH*4;          // Wh1 sliced [u/4][j][4] (4 MB)
constexpr size_t OFF_WS2  = OFF_WS1  + (size_t)kH*kH*4;          // W12 sliced
constexpr size_t OFF_WS3  = OFF_WS2  + (size_t)kH*kH*4;          // Wh2 sliced
constexpr size_t OFF_S1R  = OFF_WS3  + (size_t)kH*kH*4;          // 2 x 1024 u64 rows (bits=batch)
constexpr size_t OFF_S2R  = OFF_S1R  + 2*kH*8;
constexpr size_t OFF_CNT  = OFF_S2R  + 2*kH*8;                   // cnt[b][u] u32 (256 KB)
constexpr size_t OFF_BAR  = OFF_CNT  + (size_t)kB*kH*4;          // barrier (64 B)

// cross-block data via agent-scope atomics (per-XCD L2s not coherent)
__device__ __forceinline__ uint64_t ld64(const uint64_t* p) {
  return __hip_atomic_load(p, __ATOMIC_RELAXED, __HIP_MEMORY_SCOPE_AGENT);
}
__device__ __forceinline__ void st64(uint64_t* p, uint64_t v) {
  __hip_atomic_store(p, v, __ATOMIC_RELAXED, __HIP_MEMORY_SCOPE_AGENT);
}

// monotonic-generation grid barrier — the R0/R1-proven flat design (fastest of the
// four sync variants tested; R7/R8/R9 "improvements" all regressed by adding LLC
// polling traffic, which inflates the latency of the spike-row loads).
__device__ __forceinline__ void gridbar(uint32_t* bar, uint32_t& mygen) {
  __syncthreads();
  if (threadIdx.x == 0) {
    uint32_t g = mygen + 1;
    uint32_t a = __hip_atomic_fetch_add(&bar[0], 1u, __ATOMIC_ACQ_REL, __HIP_MEMORY_SCOPE_AGENT);
    if (a == (uint32_t)(gridDim.x - 1)) {
      __hip_atomic_store(&bar[0], 0u, __ATOMIC_RELAXED, __HIP_MEMORY_SCOPE_AGENT);
      __hip_atomic_store(&bar[1], g,  __ATOMIC_RELEASE, __HIP_MEMORY_SCOPE_AGENT);
    } else {
      while (__hip_atomic_load(&bar[1], __ATOMIC_ACQUIRE, __HIP_MEMORY_SCOPE_AGENT) < g)
        __builtin_amdgcn_s_sleep(1);
    }
  }
  __syncthreads();
  mygen = mygen + 1;
}

// ---------- transpose f32 in[R][C] -> out[C][R] (for WinT) ----------
__global__ void transpose_k(const float* __restrict__ in, float* __restrict__ out,
                            int R, int C) {
  __shared__ float tile[32][33];
  int c0 = blockIdx.x * 32, r0 = blockIdx.y * 32;
  int tx = threadIdx.x, ty = threadIdx.y;           // (32,8)
  for (int k = 0; k < 32; k += 8)
    tile[ty + k][tx] = in[(size_t)(r0 + ty + k) * C + c0 + tx];
  __syncthreads();
  for (int k = 0; k < 32; k += 8)
    out[(size_t)(c0 + ty + k) * R + r0 + tx] = tile[tx][ty + k];
}

// ---------- W[1024][1024] -> sliced S[(u>>2)*1024 + j][4] with S[..][q] = W[4Z+q][j] ----------
__global__ void wtr_sl(const float* __restrict__ in, float* __restrict__ out) {
  int u = blockIdx.x;
  int j = blockIdx.y * 256 + threadIdx.x;
  float v = in[(size_t)u * kH + j];
  out[((size_t)(u >> 2) * kH + j) * 4 + (u & 3)] = v;
}

// ---------- U2[t][b][u] = x@W_in.T + b_in  (R4's bit-exact-proven kernel, unchanged) ----------
__global__ __launch_bounds__(256) void uproj(const float* __restrict__ x,
                                             const float* __restrict__ WinT,
                                             const float* __restrict__ b_in,
                                             float* __restrict__ U2) {
  const int t    = blockIdx.x;                 // 512
  const int uc   = blockIdx.y;                 // 16
  const int lane = threadIdx.x & 63;
  const int wvu  = __builtin_amdgcn_readfirstlane(threadIdx.x >> 6);  // 0..3
  const int u    = uc * 64 + lane;
  const int b0   = wvu * 16;
  float acc[16];
  #pragma unroll
  for (int i = 0; i < 16; ++i) acc[i] = 0.0f;
  for (int k = 0; k < kD; k += 4) {
    float w0 = WinT[(size_t)(k + 0) * kH + u];
    float w1 = WinT[(size_t)(k + 1) * kH + u];
    float w2 = WinT[(size_t)(k + 2) * kH + u];
    float w3 = WinT[(size_t)(k + 3) * kH + u];
    #pragma unroll
    for (int bb = 0; bb < 16; ++bb) {
      const float4 xv = *(const float4*)(x + ((size_t)(b0 + bb) * kT + t) * kD + k);
      acc[bb] = __fmaf_rn(xv.x, w0, acc[bb]);   // ascending k, single chain: np-exact
      acc[bb] = __fmaf_rn(xv.y, w1, acc[bb]);
      acc[bb] = __fmaf_rn(xv.z, w2, acc[bb]);
      acc[bb] = __fmaf_rn(xv.w, w3, acc[bb]);
    }
  }
  float bi = b_in[u];
  #pragma unroll
  for (int bb = 0; bb < 16; ++bb)
    U2[((size_t)t * kB + (b0 + bb)) * kH + u] = __fadd_rn(acc[bb], bi);
}

// sequential-j chain over 1024 spike-gated weights from LDS; bit-exact vs R4:
// fma(w, sf, B) with sf in {0,1} == fadd(B, bit?w:0); B starts +0 and RN cancellation
// yields +0, so B is never -0 and the ±0 corners coincide.
// R10: `rows` now points to an LDS-staged copy of the mask buffer (ds_read_b64
// instead of agent-scope LLC loads). Readlane values per (g,lane) are identical ->
// bit-exact. 1-group-ahead prefetch kept (hides the small ds latency).
__device__ __forceinline__ void chain1024(const uint64_t* rows, const float4* wlds,
                                          int lane, float acc[4], float fone) {
  float4 bufA[8], bufB[8];                              // static-indexed only (no scratch)
  uint64_t cur = rows[lane];                            // group 0: lane L holds word j=L
  #pragma unroll
  for (int i = 0; i < 8; ++i) bufA[i] = wlds[i];        // preload j=0..7
  #pragma unroll 1
  for (int g = 0; g < 16; ++g) {
    uint64_t nxt = (g < 15) ? rows[(g + 1) * 64 + lane] : 0ull;  // prefetch next group
    uint32_t lo = (uint32_t)cur, hi = (uint32_t)(cur >> 32);
    const float4* wg = wlds + g * 64;
    #pragma unroll
    for (int sb = 0; sb < 8; ++sb) {                    // 8 sub-blocks of 8 jj
      // issue prefetch of sub-block sb+1 into the other buffer (8x ds_read_b128)
      #pragma unroll
      for (int i = 0; i < 8; ++i) {
        float4 w = wg[(sb + 1) * 8 + i];                // sb=7,g=15 -> pad region (unused)
        if (sb & 1) bufA[i] = w; else bufB[i] = w;
      }
      // consume sub-block sb
      #pragma unroll
      for (int i = 0; i < 8; ++i) {
        const int jj = sb * 8 + i;
        uint32_t rlo = (uint32_t)__builtin_amdgcn_readlane((int)lo, jj);  // word for j=g*64+jj
        uint32_t rhi = (uint32_t)__builtin_amdgcn_readlane((int)hi, jj);
        uint64_t rw  = ((uint64_t)rhi << 32) | rlo;     // uniform -> SGPR pair
        float sf;
        asm("v_cndmask_b32 %0, 0, %1, %2" : "=v"(sf) : "v"(fone), "s"(rw));  // sf = bit(lane)
        float4 w4 = (sb & 1) ? bufB[i] : bufA[i];       // compile-time select
        acc[0] = __fmaf_rn(w4.x, sf, acc[0]);
        acc[1] = __fmaf_rn(w4.y, sf, acc[1]);
        acc[2] = __fmaf_rn(w4.z, sf, acc[2]);
        acc[3] = __fmaf_rn(w4.w, sf, acc[3]);
      }
    }
    cur = nxt;
  }
}

// ---------- persistent SNN: lanes = batch, block Z owns units 4Z..4Z+3, weights LDS-resident ----------
// R10 change: per step, the two 8 KB spike-mask buffers (s1 gen p-1, s2 gen p-2) are
// staged global->LDS with ALL loads issued back-to-back (pipelined at the LLC: one
// latency + transfer ~1.5us total), instead of each chain issuing 16 agent-scope LLC
// round trips with only 0.37us of compute cover each (the hypothesized ~18us/step stall).
__global__ __launch_bounds__(NTHR, 1) void snn6(
    const float* __restrict__ U2,
    const float* __restrict__ Wh1S, const float* __restrict__ W12S,
    const float* __restrict__ Wh2S,
    const float* __restrict__ b_h1, const float* __restrict__ b_12,
    const float* __restrict__ b_h2,
    uint64_t* s1rows, uint64_t* s2rows, uint32_t* cnt2, uint32_t* bar)
{
  __shared__ float4 ldsW[3][kH + 8];   // ~48.4 KB: per-role 4-unit weight slice + prefetch pad
  __shared__ float  xch[4][64];        // B2 exchange (Wh2 wave -> W12 wave)
  __shared__ uint64_t m1[kH];          // 8 KB: staged s1 gen p-1 masks
  __shared__ uint64_t m2[kH];          // 8 KB: staged s2 gen p-2 masks

  const int tid  = threadIdx.x;
  const int lane = tid & 63;                                          // batch
  const int wv   = __builtin_amdgcn_readfirstlane(tid >> 6);          // role 0/1/2
  const int Z    = blockIdx.x;
  uint32_t mygen = 0;
  const float fone = 1.0f;

  // ---- one-time: preload this role's 16 KB weight slice into LDS (coalesced)
  {
    const float* Wsrc = (wv == 0) ? Wh1S : (wv == 1) ? W12S : Wh2S;
    const float4* gs = (const float4*)Wsrc + (size_t)Z * kH;
    #pragma unroll
    for (int i = 0; i < 16; ++i) {
      int idx = i * 64 + lane;
      ldsW[wv][idx] = gs[idx];
    }
  }

  // ---- zero both generations of both spike-row buffers
  {
    int idx = Z * NTHR + tid;
    if (idx < 2 * kH) { st64(&s1rows[idx], 0ull); st64(&s2rows[idx], 0ull); }
  }
  gridbar(bar, mygen);   // also makes LDS preload visible block-wide

  float bA[4];           // role bias: b_h1 / b_12 / b_h2 for units 4Z..4Z+3
  float bh2v[4];         // W12 wave also needs b_h2 for the combine
  float v[4];            // membrane state per (unit q, batch lane)
  float B1[4];           // W12 wave: stashed partial across syncthreads
  uint32_t cnt[4] = {0, 0, 0, 0};
  #pragma unroll
  for (int q = 0; q < 4; ++q) {
    v[q] = 0.0f;
    B1[q] = 0.0f;
    bA[q]   = (wv == 0) ? b_h1[4 * Z + q] : (wv == 1) ? b_12[4 * Z + q] : b_h2[4 * Z + q];
    bh2v[q] = b_h2[4 * Z + q];
  }

  for (int p = 0; p <= kT; ++p) {
    const uint64_t* r1g = s1rows + ((p & 1) ^ 1) * kH;   // s1 gen p-1
    uint64_t*       w1g = s1rows + (p & 1) * kH;         // s1 gen p
    const uint64_t* r2g = s2rows + (p & 1) * kH;         // s2 gen p-2
    uint64_t*       w2g = s2rows + ((p & 1) ^ 1) * kH;   // s2 gen p-1

    // ---- stage masks global->LDS. All loads issued before any LDS write:
    // 8-16 outstanding LLC reads pipeline (one exposed latency per wave, not 16).
    // wv0 stages s1 groups 0-7 (also consumed by wv1), wv1 stages s1 groups 8-15,
    // wv2 stages s2 (its own operand). Unconditional: at p=0/p=kT the skipped
    // roles still stage for the roles that do run; zeroed gens cover p<2 reads.
    if (wv == 0) {
      uint64_t t0[8];
      #pragma unroll
      for (int g = 0; g < 8; ++g) t0[g] = ld64(&r1g[g * 64 + lane]);
      #pragma unroll
      for (int g = 0; g < 8; ++g) m1[g * 64 + lane] = t0[g];
    } else if (wv == 1) {
      uint64_t t0[8];
      #pragma unroll
      for (int g = 0; g < 8; ++g) t0[g] = ld64(&r1g[(8 + g) * 64 + lane]);
      #pragma unroll
      for (int g = 0; g < 8; ++g) m1[(8 + g) * 64 + lane] = t0[g];
    } else {
      uint64_t t0[16];
      #pragma unroll
      for (int g = 0; g < 16; ++g) t0[g] = ld64(&r2g[g * 64 + lane]);
      #pragma unroll
      for (int g = 0; g < 16; ++g) m2[g * 64 + lane] = t0[g];
    }
    __syncthreads();   // staged masks visible block-wide

    if (wv == 0) {
      if (p < kT) {   // L1 step t=p
        // prefetch A early (no deps on the chain): latency hidden by chain1024
        float4 A4 = *(const float4*)(U2 + ((size_t)p * kB + lane) * kH + 4 * Z);
        float acc[4] = {0.f, 0.f, 0.f, 0.f};
        chain1024(m1, ldsW[0], lane, acc, fone);                 // s1(p-1)@W_h1.T
        float A[4] = {A4.x, A4.y, A4.z, A4.w};
        #pragma unroll
        for (int q = 0; q < 4; ++q) {
          float h = __fadd_rn(__fadd_rn(A[q], acc[q]), bA[q]);   // ((x@W+b_in)+rec)+b_h1
          v[q] = __fadd_rn(__fmul_rn(0.9f, v[q]), h);
          bool s = (v[q] >= 1.0f);
          if (s) v[q] = __fsub_rn(v[q], 1.0f);
          uint64_t m = __ballot(s);                              // bits = batches
          if (lane == 0) st64(&w1g[4 * Z + q], m);
        }
      }
    } else if (wv == 1) {
      if (p >= 1) {   // L2 step t=p-1, part 1: B1 = s1(p-1)@W_12.T
        float acc[4] = {0.f, 0.f, 0.f, 0.f};
        chain1024(m1, ldsW[1], lane, acc, fone);
        #pragma unroll
        for (int q = 0; q < 4; ++q) B1[q] = acc[q];
      }
    } else {
      if (p >= 1) {   // L2 part 2: B2 = s2(p-2)@W_h2.T
        float acc[4] = {0.f, 0.f, 0.f, 0.f};
        chain1024(m2, ldsW[2], lane, acc, fone);
        #pragma unroll
        for (int q = 0; q < 4; ++q) xch[q][lane] = acc[q];
      }
    }
    __syncthreads();
    if (wv == 1 && p >= 1) {   // combine + LIF2 + publish (exact R4 op order)
      #pragma unroll
      for (int q = 0; q < 4; ++q) {
        float C = __fadd_rn(B1[q], bA[q]);                        // B1 + b_12
        float h = __fadd_rn(__fadd_rn(C, xch[q][lane]), bh2v[q]); // (C+B2)+b_h2
        v[q] = __fadd_rn(__fmul_rn(0.9f, v[q]), h);
        bool s = (v[q] >= 1.0f);
        if (s) { v[q] = __fsub_rn(v[q], 1.0f); cnt[q]++; }
        uint64_t m = __ballot(s);
        if (lane == 0) st64(&w2g[4 * Z + q], m);
      }
    }
    gridbar(bar, mygen);
  }

  if (wv == 1) {
    #pragma unroll
    for (int q = 0; q < 4; ++q) cnt2[(size_t)lane * kH + 4 * Z + q] = cnt[q];
  }
}

// ---------- exact f64 readout: out[b][o] = sum_j cnt[b][j]*W_out[o][j] + 512*b_out[o] ----------
__global__ void readout(const uint32_t* __restrict__ cnt2, const float* __restrict__ W_out,
                        const float* __restrict__ b_out, float* __restrict__ out) {
  const int b = blockIdx.x;    // 64
  const int o = threadIdx.x;   // 256
  double po = 512.0 * (double)b_out[o];
  for (int j = 0; j < kH; j += 4) {
    uint4  c4 = *(const uint4*)(cnt2 + (size_t)b * kH + j);
    float4 w4 = *(const float4*)(W_out + (size_t)o * kH + j);
    po = fma((double)c4.x, (double)w4.x, po);
    po = fma((double)c4.y, (double)w4.y, po);
    po = fma((double)c4.z, (double)w4.z, po);
    po = fma((double)c4.w, (double)w4.w, po);
  }
  out[(size_t)b * kO + o] = (float)po;
}

extern "C" void kernel_launch(void* const* d_in, const int* in_sizes, int n_in,
                              void* d_out, int out_size, void* d_ws, size_t ws_size,
                              hipStream_t stream) {
  (void)in_sizes; (void)n_in; (void)out_size; (void)ws_size;
  const float* x     = (const float*)d_in[0];
  const float* W_in  = (const float*)d_in[1];
  const float* pb_in = (const float*)d_in[2];
  const float* W_h1  = (const float*)d_in[3];
  const float* pb_h1 = (const float*)d_in[4];
  const float* W_12  = (const float*)d_in[5];
  const float* pb_12 = (const float*)d_in[6];
  const float* W_h2  = (const float*)d_in[7];
  const float* pb_h2 = (const float*)d_in[8];
  const float* W_out = (const float*)d_in[9];
  const float* pb_out= (const float*)d_in[10];
  float* out = (float*)d_out;

  char* ws = (char*)d_ws;
  float*    U2   = (float*)   (ws + OFF_U2);
  float*    WinT = (float*)   (ws + OFF_WINT);
  float*    Wh1S = (float*)   (ws + OFF_WS1);
  float*    W12S = (float*)   (ws + OFF_WS2);
  float*    Wh2S = (float*)   (ws + OFF_WS3);
  uint64_t* s1r  = (uint64_t*)(ws + OFF_S1R);
  uint64_t* s2r  = (uint64_t*)(ws + OFF_S2R);
  uint32_t* cnt2 = (uint32_t*)(ws + OFF_CNT);
  uint32_t* bar  = (uint32_t*)(ws + OFF_BAR);

  hipMemsetAsync(bar, 0, 64, stream);
  hipLaunchKernelGGL(transpose_k, dim3(kD / 32, kH / 32), dim3(32, 8), 0, stream,
                     W_in, WinT, kH, kD);
  hipLaunchKernelGGL(wtr_sl, dim3(kH, 4), dim3(256), 0, stream, W_h1, Wh1S);
  hipLaunchKernelGGL(wtr_sl, dim3(kH, 4), dim3(256), 0, stream, W_12, W12S);
  hipLaunchKernelGGL(wtr_sl, dim3(kH, 4), dim3(256), 0, stream, W_h2, Wh2S);
  hipLaunchKernelGGL(uproj, dim3(kT, 16), dim3(256), 0, stream, x, WinT, pb_in, U2);

  void* args[] = {(void*)&U2, (void*)&Wh1S, (void*)&W12S, (void*)&Wh2S,
                  (void*)&pb_h1, (void*)&pb_12, (void*)&pb_h2,
                  (void*)&s1r, (void*)&s2r, (void*)&cnt2, (void*)&bar};
  hipLaunchCooperativeKernel((void*)snn6, dim3(NBLK), dim3(NTHR), args, 0, stream);

  hipLaunchKernelGGL(readout, dim3(kB), dim3(kO), 0, stream, cnt2, W_out, pb_out, out);
}

// Round 7
// 17835.834 us; speedup vs baseline: 2.3647x; 1.1892x over previous
//
#include <hip/hip_runtime.h>
#include <stdint.h>

// ---------------- problem sizes ----------------
constexpr int kB = 64, kT = 512, kD = 512, kH = 1024, kO = 256;

// ---------------- grid config ----------------
constexpr int NBLK = 256;   // block Z owns units 4Z..4Z+3 of L1 AND L2, all 64 batches
constexpr int NTHR = 192;   // wave 0: L1(Wh1)  wave 1: W12(+LIF2+combine)  wave 2: Wh2

// ---------------- ws layout (bytes) — total ~142.3 MB (== R4's proven footprint) ----------------
constexpr size_t OFF_U2   = 0;                                   // U2[t][b][u] f32 (128 MB) = x@W_in.T + b_in
constexpr size_t OFF_WINT = OFF_U2   + (size_t)kT*kB*kH*4;       // WinT[k][u] f32 (2 MB)
constexpr size_t OFF_WS1  = OFF_WINT + (size_t)kD*kH*4;          // Wh1 sliced [u/4][j][4] (4 MB)
constexpr size_t OFF_WS2  = OFF_WS1  + (size_t)kH*kH*4;          // W12 sliced
constexpr size_t OFF_WS3  = OFF_WS2  + (size_t)kH*kH*4;          // Wh2 sliced
constexpr size_t OFF_S1R  = OFF_WS3  + (size_t)kH*kH*4;          // 2 x 1024 u64 rows (bits=batch)
constexpr size_t OFF_S2R  = OFF_S1R  + 2*kH*8;
constexpr size_t OFF_CNT  = OFF_S2R  + 2*kH*8;                   // cnt[b][u] u32 (256 KB)
constexpr size_t OFF_BAR  = OFF_CNT  + (size_t)kB*kH*4;          // barrier (64 B)

// cross-block data via agent-scope atomics (per-XCD L2s not coherent)
__device__ __forceinline__ uint64_t ld64(const uint64_t* p) {
  return __hip_atomic_load(p, __ATOMIC_RELAXED, __HIP_MEMORY_SCOPE_AGENT);
}
__device__ __forceinline__ void st64(uint64_t* p, uint64_t v) {
  __hip_atomic_store(p, v, __ATOMIC_RELAXED, __HIP_MEMORY_SCOPE_AGENT);
}

// R11 grid barrier: flat R0 structure, but the spin uses RELAXED agent loads.
// WHY: an agent-scope ACQUIRE load emits buffer_inv (L2 invalidate) after every
// load on gfx94x+. 255 pollers x ~5 polls/us x 24us window = ~30K L2-invalidates
// per step across the 8 shared per-XCD L2s — an invalidation storm that throttles
// the arrival RMWs and release visibility behind the same L2s (the measured idle
// grew monotonically with acquire-poll count across R5/R7/R8/R9). Relaxed sc1
// loads read the LLC without inv. One ACQUIRE load after spin-success provides
// the hb edge (all cross-block mask data is sc1-relaxed at the LLC anyway, made
// globally visible by each writer's ACQ_REL arrival RMW drain).
__device__ __forceinline__ void gridbar(uint32_t* bar, uint32_t& mygen) {
  __syncthreads();
  if (threadIdx.x == 0) {
    uint32_t g = mygen + 1;
    uint32_t a = __hip_atomic_fetch_add(&bar[0], 1u, __ATOMIC_ACQ_REL, __HIP_MEMORY_SCOPE_AGENT);
    if (a == (uint32_t)(gridDim.x - 1)) {
      __hip_atomic_store(&bar[0], 0u, __ATOMIC_RELAXED, __HIP_MEMORY_SCOPE_AGENT);
      __hip_atomic_store(&bar[1], g,  __ATOMIC_RELEASE, __HIP_MEMORY_SCOPE_AGENT);
    } else {
      while (__hip_atomic_load(&bar[1], __ATOMIC_RELAXED, __HIP_MEMORY_SCOPE_AGENT) < g)
        __builtin_amdgcn_s_sleep(1);
      (void)__hip_atomic_load(&bar[1], __ATOMIC_ACQUIRE, __HIP_MEMORY_SCOPE_AGENT);  // single inv
    }
  }
  __syncthreads();
  mygen = mygen + 1;
}

// ---------- transpose f32 in[R][C] -> out[C][R] (for WinT) ----------
__global__ void transpose_k(const float* __restrict__ in, float* __restrict__ out,
                            int R, int C) {
  __shared__ float tile[32][33];
  int c0 = blockIdx.x * 32, r0 = blockIdx.y * 32;
  int tx = threadIdx.x, ty = threadIdx.y;           // (32,8)
  for (int k = 0; k < 32; k += 8)
    tile[ty + k][tx] = in[(size_t)(r0 + ty + k) * C + c0 + tx];
  __syncthreads();
  for (int k = 0; k < 32; k += 8)
    out[(size_t)(c0 + ty + k) * R + r0 + tx] = tile[tx][ty + k];
}

// ---------- W[1024][1024] -> sliced S[(u>>2)*1024 + j][4] with S[..][q] = W[4Z+q][j] ----------
__global__ void wtr_sl(const float* __restrict__ in, float* __restrict__ out) {
  int u = blockIdx.x;
  int j = blockIdx.y * 256 + threadIdx.x;
  float v = in[(size_t)u * kH + j];
  out[((size_t)(u >> 2) * kH + j) * 4 + (u & 3)] = v;
}

// ---------- U2[t][b][u] = x@W_in.T + b_in  (R4's bit-exact-proven kernel, unchanged) ----------
__global__ __launch_bounds__(256) void uproj(const float* __restrict__ x,
                                             const float* __restrict__ WinT,
                                             const float* __restrict__ b_in,
                                             float* __restrict__ U2) {
  const int t    = blockIdx.x;                 // 512
  const int uc   = blockIdx.y;                 // 16
  const int lane = threadIdx.x & 63;
  const int wvu  = __builtin_amdgcn_readfirstlane(threadIdx.x >> 6);  // 0..3
  const int u    = uc * 64 + lane;
  const int b0   = wvu * 16;
  float acc[16];
  #pragma unroll
  for (int i = 0; i < 16; ++i) acc[i] = 0.0f;
  for (int k = 0; k < kD; k += 4) {
    float w0 = WinT[(size_t)(k + 0) * kH + u];
    float w1 = WinT[(size_t)(k + 1) * kH + u];
    float w2 = WinT[(size_t)(k + 2) * kH + u];
    float w3 = WinT[(size_t)(k + 3) * kH + u];
    #pragma unroll
    for (int bb = 0; bb < 16; ++bb) {
      const float4 xv = *(const float4*)(x + ((size_t)(b0 + bb) * kT + t) * kD + k);
      acc[bb] = __fmaf_rn(xv.x, w0, acc[bb]);   // ascending k, single chain: np-exact
      acc[bb] = __fmaf_rn(xv.y, w1, acc[bb]);
      acc[bb] = __fmaf_rn(xv.z, w2, acc[bb]);
      acc[bb] = __fmaf_rn(xv.w, w3, acc[bb]);
    }
  }
  float bi = b_in[u];
  #pragma unroll
  for (int bb = 0; bb < 16; ++bb)
    U2[((size_t)t * kB + (b0 + bb)) * kH + u] = __fadd_rn(acc[bb], bi);
}

// sequential-j chain over 1024 spike-gated weights from LDS; bit-exact vs R4:
// fma(w, sf, B) with sf in {0,1} == fadd(B, bit?w:0); B starts +0 and RN cancellation
// yields +0, so B is never -0 and the ±0 corners coincide.
// `rows` points to the LDS-staged mask copy (R10); readlane values per (g,lane)
// identical -> bit-exact.
__device__ __forceinline__ void chain1024(const uint64_t* rows, const float4* wlds,
                                          int lane, float acc[4], float fone) {
  float4 bufA[8], bufB[8];                              // static-indexed only (no scratch)
  uint64_t cur = rows[lane];                            // group 0: lane L holds word j=L
  #pragma unroll
  for (int i = 0; i < 8; ++i) bufA[i] = wlds[i];        // preload j=0..7
  #pragma unroll 1
  for (int g = 0; g < 16; ++g) {
    uint64_t nxt = (g < 15) ? rows[(g + 1) * 64 + lane] : 0ull;  // prefetch next group
    uint32_t lo = (uint32_t)cur, hi = (uint32_t)(cur >> 32);
    const float4* wg = wlds + g * 64;
    #pragma unroll
    for (int sb = 0; sb < 8; ++sb) {                    // 8 sub-blocks of 8 jj
      // issue prefetch of sub-block sb+1 into the other buffer (8x ds_read_b128)
      #pragma unroll
      for (int i = 0; i < 8; ++i) {
        float4 w = wg[(sb + 1) * 8 + i];                // sb=7,g=15 -> pad region (unused)
        if (sb & 1) bufA[i] = w; else bufB[i] = w;
      }
      // consume sub-block sb
      #pragma unroll
      for (int i = 0; i < 8; ++i) {
        const int jj = sb * 8 + i;
        uint32_t rlo = (uint32_t)__builtin_amdgcn_readlane((int)lo, jj);  // word for j=g*64+jj
        uint32_t rhi = (uint32_t)__builtin_amdgcn_readlane((int)hi, jj);
        uint64_t rw  = ((uint64_t)rhi << 32) | rlo;     // uniform -> SGPR pair
        float sf;
        asm("v_cndmask_b32 %0, 0, %1, %2" : "=v"(sf) : "v"(fone), "s"(rw));  // sf = bit(lane)
        float4 w4 = (sb & 1) ? bufB[i] : bufA[i];       // compile-time select
        acc[0] = __fmaf_rn(w4.x, sf, acc[0]);
        acc[1] = __fmaf_rn(w4.y, sf, acc[1]);
        acc[2] = __fmaf_rn(w4.z, sf, acc[2]);
        acc[3] = __fmaf_rn(w4.w, sf, acc[3]);
      }
    }
    cur = nxt;
  }
}

// ---------- persistent SNN: lanes = batch, block Z owns units 4Z..4Z+3, weights LDS-resident ----------
// Masks staged global->LDS per step, all loads back-to-back (R10, pipelined at LLC).
__global__ __launch_bounds__(NTHR, 1) void snn6(
    const float* __restrict__ U2,
    const float* __restrict__ Wh1S, const float* __restrict__ W12S,
    const float* __restrict__ Wh2S,
    const float* __restrict__ b_h1, const float* __restrict__ b_12,
    const float* __restrict__ b_h2,
    uint64_t* s1rows, uint64_t* s2rows, uint32_t* cnt2, uint32_t* bar)
{
  __shared__ float4 ldsW[3][kH + 8];   // ~48.4 KB: per-role 4-unit weight slice + prefetch pad
  __shared__ float  xch[4][64];        // B2 exchange (Wh2 wave -> W12 wave)
  __shared__ uint64_t m1[kH];          // 8 KB: staged s1 gen p-1 masks
  __shared__ uint64_t m2[kH];          // 8 KB: staged s2 gen p-2 masks

  const int tid  = threadIdx.x;
  const int lane = tid & 63;                                          // batch
  const int wv   = __builtin_amdgcn_readfirstlane(tid >> 6);          // role 0/1/2
  const int Z    = blockIdx.x;
  uint32_t mygen = 0;
  const float fone = 1.0f;

  // ---- one-time: preload this role's 16 KB weight slice into LDS (coalesced)
  {
    const float* Wsrc = (wv == 0) ? Wh1S : (wv == 1) ? W12S : Wh2S;
    const float4* gs = (const float4*)Wsrc + (size_t)Z * kH;
    #pragma unroll
    for (int i = 0; i < 16; ++i) {
      int idx = i * 64 + lane;
      ldsW[wv][idx] = gs[idx];
    }
  }

  // ---- zero both generations of both spike-row buffers
  {
    int idx = Z * NTHR + tid;
    if (idx < 2 * kH) { st64(&s1rows[idx], 0ull); st64(&s2rows[idx], 0ull); }
  }
  gridbar(bar, mygen);   // also makes LDS preload visible block-wide

  float bA[4];           // role bias: b_h1 / b_12 / b_h2 for units 4Z..4Z+3
  float bh2v[4];         // W12 wave also needs b_h2 for the combine
  float v[4];            // membrane state per (unit q, batch lane)
  float B1[4];           // W12 wave: stashed partial across syncthreads
  uint32_t cnt[4] = {0, 0, 0, 0};
  #pragma unroll
  for (int q = 0; q < 4; ++q) {
    v[q] = 0.0f;
    B1[q] = 0.0f;
    bA[q]   = (wv == 0) ? b_h1[4 * Z + q] : (wv == 1) ? b_12[4 * Z + q] : b_h2[4 * Z + q];
    bh2v[q] = b_h2[4 * Z + q];
  }

  for (int p = 0; p <= kT; ++p) {
    const uint64_t* r1g = s1rows + ((p & 1) ^ 1) * kH;   // s1 gen p-1
    uint64_t*       w1g = s1rows + (p & 1) * kH;         // s1 gen p
    const uint64_t* r2g = s2rows + (p & 1) * kH;         // s2 gen p-2
    uint64_t*       w2g = s2rows + ((p & 1) ^ 1) * kH;   // s2 gen p-1

    // ---- stage masks global->LDS, all loads issued before any LDS write
    if (wv == 0) {
      uint64_t t0[8];
      #pragma unroll
      for (int g = 0; g < 8; ++g) t0[g] = ld64(&r1g[g * 64 + lane]);
      #pragma unroll
      for (int g = 0; g < 8; ++g) m1[g * 64 + lane] = t0[g];
    } else if (wv == 1) {
      uint64_t t0[8];
      #pragma unroll
      for (int g = 0; g < 8; ++g) t0[g] = ld64(&r1g[(8 + g) * 64 + lane]);
      #pragma unroll
      for (int g = 0; g < 8; ++g) m1[(8 + g) * 64 + lane] = t0[g];
    } else {
      uint64_t t0[16];
      #pragma unroll
      for (int g = 0; g < 16; ++g) t0[g] = ld64(&r2g[g * 64 + lane]);
      #pragma unroll
      for (int g = 0; g < 16; ++g) m2[g * 64 + lane] = t0[g];
    }
    __syncthreads();   // staged masks visible block-wide

    if (wv == 0) {
      if (p < kT) {   // L1 step t=p
        // prefetch A early (no deps on the chain): latency hidden by chain1024
        float4 A4 = *(const float4*)(U2 + ((size_t)p * kB + lane) * kH + 4 * Z);
        float acc[4] = {0.f, 0.f, 0.f, 0.f};
        chain1024(m1, ldsW[0], lane, acc, fone);                 // s1(p-1)@W_h1.T
        float A[4] = {A4.x, A4.y, A4.z, A4.w};
        #pragma unroll
        for (int q = 0; q < 4; ++q) {
          float h = __fadd_rn(__fadd_rn(A[q], acc[q]), bA[q]);   // ((x@W+b_in)+rec)+b_h1
          v[q] = __fadd_rn(__fmul_rn(0.9f, v[q]), h);
          bool s = (v[q] >= 1.0f);
          if (s) v[q] = __fsub_rn(v[q], 1.0f);
          uint64_t m = __ballot(s);                              // bits = batches
          if (lane == 0) st64(&w1g[4 * Z + q], m);
        }
      }
    } else if (wv == 1) {
      if (p >= 1) {   // L2 step t=p-1, part 1: B1 = s1(p-1)@W_12.T
        float acc[4] = {0.f, 0.f, 0.f, 0.f};
        chain1024(m1, ldsW[1], lane, acc, fone);
        #pragma unroll
        for (int q = 0; q < 4; ++q) B1[q] = acc[q];
      }
    } else {
      if (p >= 1) {   // L2 part 2: B2 = s2(p-2)@W_h2.T
        float acc[4] = {0.f, 0.f, 0.f, 0.f};
        chain1024(m2, ldsW[2], lane, acc, fone);
        #pragma unroll
        for (int q = 0; q < 4; ++q) xch[q][lane] = acc[q];
      }
    }
    __syncthreads();
    if (wv == 1 && p >= 1) {   // combine + LIF2 + publish (exact R4 op order)
      #pragma unroll
      for (int q = 0; q < 4; ++q) {
        float C = __fadd_rn(B1[q], bA[q]);                        // B1 + b_12
        float h = __fadd_rn(__fadd_rn(C, xch[q][lane]), bh2v[q]); // (C+B2)+b_h2
        v[q] = __fadd_rn(__fmul_rn(0.9f, v[q]), h);
        bool s = (v[q] >= 1.0f);
        if (s) { v[q] = __fsub_rn(v[q], 1.0f); cnt[q]++; }
        uint64_t m = __ballot(s);
        if (lane == 0) st64(&w2g[4 * Z + q], m);
      }
    }
    gridbar(bar, mygen);
  }

  if (wv == 1) {
    #pragma unroll
    for (int q = 0; q < 4; ++q) cnt2[(size_t)lane * kH + 4 * Z + q] = cnt[q];
  }
}

// ---------- exact f64 readout: out[b][o] = sum_j cnt[b][j]*W_out[o][j] + 512*b_out[o] ----------
__global__ void readout(const uint32_t* __restrict__ cnt2, const float* __restrict__ W_out,
                        const float* __restrict__ b_out, float* __restrict__ out) {
  const int b = blockIdx.x;    // 64
  const int o = threadIdx.x;   // 256
  double po = 512.0 * (double)b_out[o];
  for (int j = 0; j < kH; j += 4) {
    uint4  c4 = *(const uint4*)(cnt2 + (size_t)b * kH + j);
    float4 w4 = *(const float4*)(W_out + (size_t)o * kH + j);
    po = fma((double)c4.x, (double)w4.x, po);
    po = fma((double)c4.y, (double)w4.y, po);
    po = fma((double)c4.z, (double)w4.z, po);
    po = fma((double)c4.w, (double)w4.w, po);
  }
  out[(size_t)b * kO + o] = (float)po;
}

extern "C" void kernel_launch(void* const* d_in, const int* in_sizes, int n_in,
                              void* d_out, int out_size, void* d_ws, size_t ws_size,
                              hipStream_t stream) {
  (void)in_sizes; (void)n_in; (void)out_size; (void)ws_size;
  const float* x     = (const float*)d_in[0];
  const float* W_in  = (const float*)d_in[1];
  const float* pb_in = (const float*)d_in[2];
  const float* W_h1  = (const float*)d_in[3];
  const float* pb_h1 = (const float*)d_in[4];
  const float* W_12  = (const float*)d_in[5];
  const float* pb_12 = (const float*)d_in[6];
  const float* W_h2  = (const float*)d_in[7];
  const float* pb_h2 = (const float*)d_in[8];
  const float* W_out = (const float*)d_in[9];
  const float* pb_out= (const float*)d_in[10];
  float* out = (float*)d_out;

  char* ws = (char*)d_ws;
  float*    U2   = (float*)   (ws + OFF_U2);
  float*    WinT = (float*)   (ws + OFF_WINT);
  float*    Wh1S = (float*)   (ws + OFF_WS1);
  float*    W12S = (float*)   (ws + OFF_WS2);
  float*    Wh2S = (float*)   (ws + OFF_WS3);
  uint64_t* s1r  = (uint64_t*)(ws + OFF_S1R);
  uint64_t* s2r  = (uint64_t*)(ws + OFF_S2R);
  uint32_t* cnt2 = (uint32_t*)(ws + OFF_CNT);
  uint32_t* bar  = (uint32_t*)(ws + OFF_BAR);

  hipMemsetAsync(bar, 0, 64, stream);
  hipLaunchKernelGGL(transpose_k, dim3(kD / 32, kH / 32), dim3(32, 8), 0, stream,
                     W_in, WinT, kH, kD);
  hipLaunchKernelGGL(wtr_sl, dim3(kH, 4), dim3(256), 0, stream, W_h1, Wh1S);
  hipLaunchKernelGGL(wtr_sl, dim3(kH, 4), dim3(256), 0, stream, W_12, W12S);
  hipLaunchKernelGGL(wtr_sl, dim3(kH, 4), dim3(256), 0, stream, W_h2, Wh2S);
  hipLaunchKernelGGL(uproj, dim3(kT, 16), dim3(256), 0, stream, x, WinT, pb_in, U2);

  void* args[] = {(void*)&U2, (void*)&Wh1S, (void*)&W12S, (void*)&Wh2S,
                  (void*)&pb_h1, (void*)&pb_12, (void*)&pb_h2,
                  (void*)&s1r, (void*)&s2r, (void*)&cnt2, (void*)&bar};
  hipLaunchCooperativeKernel((void*)snn6, dim3(NBLK), dim3(NTHR), args, 0, stream);

  hipLaunchKernelGGL(readout, dim3(kB), dim3(kO), 0, stream, cnt2, W_out, pb_out, out);
}

// Round 10
// 16845.226 us; speedup vs baseline: 2.5038x; 1.0588x over previous
//
#include <hip/hip_runtime.h>
#include <stdint.h>

// ---------------- problem sizes ----------------
constexpr int kB = 64, kT = 512, kD = 512, kH = 1024, kO = 256;

// ---------------- grid config ----------------
constexpr int NBLK = 256;   // block Z owns units 4Z..4Z+3 of L1 AND L2, all 64 batches
constexpr int NTHR = 192;   // wave 0: L1(Wh1)  wave 1: W12(+LIF2+combine)  wave 2: Wh2

// ---------------- ws layout (bytes) — total ~142.3 MB (== R4's proven footprint) ----------------
constexpr size_t OFF_U2   = 0;                                   // U2[t][b][u] f32 (128 MB) = x@W_in.T + b_in
constexpr size_t OFF_WINT = OFF_U2   + (size_t)kT*kB*kH*4;       // WinT[k][u] f32 (2 MB)
constexpr size_t OFF_WS1  = OFF_WINT + (size_t)kD*kH*4;          // Wh1 sliced [u/4][j][4] (4 MB)
constexpr size_t OFF_WS2  = OFF_WS1  + (size_t)kH*kH*4;          // W12 sliced
constexpr size_t OFF_WS3  = OFF_WS2  + (size_t)kH*kH*4;          // Wh2 sliced
constexpr size_t OFF_S1R  = OFF_WS3  + (size_t)kH*kH*4;          // 2 x 1024 u64 rows (bits=batch)
constexpr size_t OFF_S2R  = OFF_S1R  + 2*kH*8;
constexpr size_t OFF_CNT  = OFF_S2R  + 2*kH*8;                   // cnt[b][u] u32 (256 KB)
constexpr size_t OFF_BAR  = OFF_CNT  + (size_t)kB*kH*4;          // barrier arena (4 KB)

// barrier arena (memset to 0 each launch):
//   arr[8] u32 @ +0, stride 128 B   (per-group arrival counters, 32 serialized RMWs each)
//   top    u32 @ +1024              (8 RMWs per generation)
//   rel    u32 @ +2048              (single release word — R11's proven poll target)
constexpr int    LINE_W    = 32;   // 128 B / 4
constexpr size_t ARN_BYTES = 4096;

// cross-block data via agent-scope atomics (per-XCD L2s not coherent)
__device__ __forceinline__ uint64_t ld64(const uint64_t* p) {
  return __hip_atomic_load(p, __ATOMIC_RELAXED, __HIP_MEMORY_SCOPE_AGENT);
}
__device__ __forceinline__ void st64(uint64_t* p, uint64_t v) {
  __hip_atomic_store(p, v, __ATOMIC_RELAXED, __HIP_MEMORY_SCOPE_AGENT);
}

// R14 grid barrier = R11's proven release/poll path (single rel word, RELAXED spin,
// s_sleep, ONE trailing ACQUIRE load = single buffer_inv) + tree ARRIVAL only.
// R11 measured: flat 256-RMW arrival + this poll path = 24.8us step (proven).
// Theory under test: the 256 serialized ACQ_REL RMWs on one LLC line are ~10us of
// the residual. Split: arr[Z&7] (8 lines x 32 RMWs, parallel) -> group-last RMWs
// top (8/gen) -> top-last release-stores rel = g.
// hb: block's ACQ_REL arrival publishes its mask stores -> group-last ACQ_REL on
// top accumulates group history -> top-last release-store rel -> poller's single
// ACQUIRE load. Monotonic counters, no reset, no ABA; arena zeroed per replay.
__device__ __forceinline__ void gridbar(uint32_t* arena, uint32_t& mygen) {
  __syncthreads();
  const uint32_t g = mygen + 1;
  if (threadIdx.x == 0) {
    const int x = blockIdx.x & 7;
    uint32_t* arr = arena + x * LINE_W;
    uint32_t* top = arena + (1024 / 4);
    uint32_t* rel = arena + (2048 / 4);
    uint32_t c = __hip_atomic_fetch_add(arr, 1u, __ATOMIC_ACQ_REL, __HIP_MEMORY_SCOPE_AGENT);
    if (c == g * 32u - 1u) {                 // last arrival in this group for gen g
      uint32_t t = __hip_atomic_fetch_add(top, 1u, __ATOMIC_ACQ_REL, __HIP_MEMORY_SCOPE_AGENT);
      if (t == g * 8u - 1u)                  // last group overall for gen g
        __hip_atomic_store(rel, g, __ATOMIC_RELEASE, __HIP_MEMORY_SCOPE_AGENT);
    }
    while (__hip_atomic_load(rel, __ATOMIC_RELAXED, __HIP_MEMORY_SCOPE_AGENT) < g)
      __builtin_amdgcn_s_sleep(1);
    (void)__hip_atomic_load(rel, __ATOMIC_ACQUIRE, __HIP_MEMORY_SCOPE_AGENT);  // single inv
  }
  __syncthreads();
  mygen = g;
}

// ---------- transpose f32 in[R][C] -> out[C][R] (for WinT) ----------
__global__ void transpose_k(const float* __restrict__ in, float* __restrict__ out,
                            int R, int C) {
  __shared__ float tile[32][33];
  int c0 = blockIdx.x * 32, r0 = blockIdx.y * 32;
  int tx = threadIdx.x, ty = threadIdx.y;           // (32,8)
  for (int k = 0; k < 32; k += 8)
    tile[ty + k][tx] = in[(size_t)(r0 + ty + k) * C + c0 + tx];
  __syncthreads();
  for (int k = 0; k < 32; k += 8)
    out[(size_t)(c0 + ty + k) * R + r0 + tx] = tile[tx][ty + k];
}

// ---------- W[1024][1024] -> sliced S[(u>>2)*1024 + j][4] with S[..][q] = W[4Z+q][j] ----------
__global__ void wtr_sl(const float* __restrict__ in, float* __restrict__ out) {
  int u = blockIdx.x;
  int j = blockIdx.y * 256 + threadIdx.x;
  float v = in[(size_t)u * kH + j];
  out[((size_t)(u >> 2) * kH + j) * 4 + (u & 3)] = v;
}

// ---------- U2[t][b][u] = x@W_in.T + b_in  (R4's bit-exact-proven kernel, unchanged) ----------
__global__ __launch_bounds__(256) void uproj(const float* __restrict__ x,
                                             const float* __restrict__ WinT,
                                             const float* __restrict__ b_in,
                                             float* __restrict__ U2) {
  const int t    = blockIdx.x;                 // 512
  const int uc   = blockIdx.y;                 // 16
  const int lane = threadIdx.x & 63;
  const int wvu  = __builtin_amdgcn_readfirstlane(threadIdx.x >> 6);  // 0..3
  const int u    = uc * 64 + lane;
  const int b0   = wvu * 16;
  float acc[16];
  #pragma unroll
  for (int i = 0; i < 16; ++i) acc[i] = 0.0f;
  for (int k = 0; k < kD; k += 4) {
    float w0 = WinT[(size_t)(k + 0) * kH + u];
    float w1 = WinT[(size_t)(k + 1) * kH + u];
    float w2 = WinT[(size_t)(k + 2) * kH + u];
    float w3 = WinT[(size_t)(k + 3) * kH + u];
    #pragma unroll
    for (int bb = 0; bb < 16; ++bb) {
      const float4 xv = *(const float4*)(x + ((size_t)(b0 + bb) * kT + t) * kD + k);
      acc[bb] = __fmaf_rn(xv.x, w0, acc[bb]);   // ascending k, single chain: np-exact
      acc[bb] = __fmaf_rn(xv.y, w1, acc[bb]);
      acc[bb] = __fmaf_rn(xv.z, w2, acc[bb]);
      acc[bb] = __fmaf_rn(xv.w, w3, acc[bb]);
    }
  }
  float bi = b_in[u];
  #pragma unroll
  for (int bb = 0; bb < 16; ++bb)
    U2[((size_t)t * kB + (b0 + bb)) * kH + u] = __fadd_rn(acc[bb], bi);
}

// sequential-j chain over 1024 spike-gated weights from LDS; bit-exact vs R4:
// fma(w, sf, B) with sf in {0,1} == fadd(B, bit?w:0); B starts +0 and RN cancellation
// yields +0, so B is never -0 and the ±0 corners coincide.
// `rows` points to the LDS-staged mask copy (R10); readlane values per (g,lane)
// identical -> bit-exact.
__device__ __forceinline__ void chain1024(const uint64_t* rows, const float4* wlds,
                                          int lane, float acc[4], float fone) {
  float4 bufA[8], bufB[8];                              // static-indexed only (no scratch)
  uint64_t cur = rows[lane];                            // group 0: lane L holds word j=L
  #pragma unroll
  for (int i = 0; i < 8; ++i) bufA[i] = wlds[i];        // preload j=0..7
  #pragma unroll 1
  for (int g = 0; g < 16; ++g) {
    uint64_t nxt = (g < 15) ? rows[(g + 1) * 64 + lane] : 0ull;  // prefetch next group
    uint32_t lo = (uint32_t)cur, hi = (uint32_t)(cur >> 32);
    const float4* wg = wlds + g * 64;
    #pragma unroll
    for (int sb = 0; sb < 8; ++sb) {                    // 8 sub-blocks of 8 jj
      // issue prefetch of sub-block sb+1 into the other buffer (8x ds_read_b128)
      #pragma unroll
      for (int i = 0; i < 8; ++i) {
        float4 w = wg[(sb + 1) * 8 + i];                // sb=7,g=15 -> pad region (unused)
        if (sb & 1) bufA[i] = w; else bufB[i] = w;
      }
      // consume sub-block sb
      #pragma unroll
      for (int i = 0; i < 8; ++i) {
        const int jj = sb * 8 + i;
        uint32_t rlo = (uint32_t)__builtin_amdgcn_readlane((int)lo, jj);  // word for j=g*64+jj
        uint32_t rhi = (uint32_t)__builtin_amdgcn_readlane((int)hi, jj);
        uint64_t rw  = ((uint64_t)rhi << 32) | rlo;     // uniform -> SGPR pair
        float sf;
        asm("v_cndmask_b32 %0, 0, %1, %2" : "=v"(sf) : "v"(fone), "s"(rw));  // sf = bit(lane)
        float4 w4 = (sb & 1) ? bufB[i] : bufA[i];       // compile-time select
        acc[0] = __fmaf_rn(w4.x, sf, acc[0]);
        acc[1] = __fmaf_rn(w4.y, sf, acc[1]);
        acc[2] = __fmaf_rn(w4.z, sf, acc[2]);
        acc[3] = __fmaf_rn(w4.w, sf, acc[3]);
      }
    }
    cur = nxt;
  }
}

// ---------- persistent SNN: lanes = batch, block Z owns units 4Z..4Z+3, weights LDS-resident ----------
// Masks staged global->LDS per step, all loads back-to-back (R10, pipelined at LLC).
__global__ __launch_bounds__(NTHR, 1) void snn6(
    const float* __restrict__ U2,
    const float* __restrict__ Wh1S, const float* __restrict__ W12S,
    const float* __restrict__ Wh2S,
    const float* __restrict__ b_h1, const float* __restrict__ b_12,
    const float* __restrict__ b_h2,
    uint64_t* s1rows, uint64_t* s2rows, uint32_t* cnt2, uint32_t* arena)
{
  __shared__ float4 ldsW[3][kH + 8];   // ~48.4 KB: per-role 4-unit weight slice + prefetch pad
  __shared__ float  xch[4][64];        // B2 exchange (Wh2 wave -> W12 wave)
  __shared__ uint64_t m1[kH];          // 8 KB: staged s1 gen p-1 masks
  __shared__ uint64_t m2[kH];          // 8 KB: staged s2 gen p-2 masks

  const int tid  = threadIdx.x;
  const int lane = tid & 63;                                          // batch
  const int wv   = __builtin_amdgcn_readfirstlane(tid >> 6);          // role 0/1/2
  const int Z    = blockIdx.x;
  uint32_t mygen = 0;
  const float fone = 1.0f;

  // ---- one-time: preload this role's 16 KB weight slice into LDS (coalesced)
  {
    const float* Wsrc = (wv == 0) ? Wh1S : (wv == 1) ? W12S : Wh2S;
    const float4* gs = (const float4*)Wsrc + (size_t)Z * kH;
    #pragma unroll
    for (int i = 0; i < 16; ++i) {
      int idx = i * 64 + lane;
      ldsW[wv][idx] = gs[idx];
    }
  }

  // ---- zero both generations of both spike-row buffers
  {
    int idx = Z * NTHR + tid;
    if (idx < 2 * kH) { st64(&s1rows[idx], 0ull); st64(&s2rows[idx], 0ull); }
  }
  gridbar(arena, mygen);   // also makes LDS preload visible block-wide

  float bA[4];           // role bias: b_h1 / b_12 / b_h2 for units 4Z..4Z+3
  float bh2v[4];         // W12 wave also needs b_h2 for the combine
  float v[4];            // membrane state per (unit q, batch lane)
  float B1[4];           // W12 wave: stashed partial across syncthreads
  uint32_t cnt[4] = {0, 0, 0, 0};
  #pragma unroll
  for (int q = 0; q < 4; ++q) {
    v[q] = 0.0f;
    B1[q] = 0.0f;
    bA[q]   = (wv == 0) ? b_h1[4 * Z + q] : (wv == 1) ? b_12[4 * Z + q] : b_h2[4 * Z + q];
    bh2v[q] = b_h2[4 * Z + q];
  }

  for (int p = 0; p <= kT; ++p) {
    const uint64_t* r1g = s1rows + ((p & 1) ^ 1) * kH;   // s1 gen p-1
    uint64_t*       w1g = s1rows + (p & 1) * kH;         // s1 gen p
    const uint64_t* r2g = s2rows + (p & 1) * kH;         // s2 gen p-2
    uint64_t*       w2g = s2rows + ((p & 1) ^ 1) * kH;   // s2 gen p-1

    // ---- stage masks global->LDS, all loads issued before any LDS write
    if (wv == 0) {
      uint64_t t0[8];
      #pragma unroll
      for (int g = 0; g < 8; ++g) t0[g] = ld64(&r1g[g * 64 + lane]);
      #pragma unroll
      for (int g = 0; g < 8; ++g) m1[g * 64 + lane] = t0[g];
    } else if (wv == 1) {
      uint64_t t0[8];
      #pragma unroll
      for (int g = 0; g < 8; ++g) t0[g] = ld64(&r1g[(8 + g) * 64 + lane]);
      #pragma unroll
      for (int g = 0; g < 8; ++g) m1[(8 + g) * 64 + lane] = t0[g];
    } else {
      uint64_t t0[16];
      #pragma unroll
      for (int g = 0; g < 16; ++g) t0[g] = ld64(&r2g[g * 64 + lane]);
      #pragma unroll
      for (int g = 0; g < 16; ++g) m2[g * 64 + lane] = t0[g];
    }
    __syncthreads();   // staged masks visible block-wide

    if (wv == 0) {
      if (p < kT) {   // L1 step t=p
        // prefetch A early (no deps on the chain): latency hidden by chain1024
        float4 A4 = *(const float4*)(U2 + ((size_t)p * kB + lane) * kH + 4 * Z);
        float acc[4] = {0.f, 0.f, 0.f, 0.f};
        chain1024(m1, ldsW[0], lane, acc, fone);                 // s1(p-1)@W_h1.T
        float A[4] = {A4.x, A4.y, A4.z, A4.w};
        #pragma unroll
        for (int q = 0; q < 4; ++q) {
          float h = __fadd_rn(__fadd_rn(A[q], acc[q]), bA[q]);   // ((x@W+b_in)+rec)+b_h1
          v[q] = __fadd_rn(__fmul_rn(0.9f, v[q]), h);
          bool s = (v[q] >= 1.0f);
          if (s) v[q] = __fsub_rn(v[q], 1.0f);
          uint64_t m = __ballot(s);                              // bits = batches
          if (lane == 0) st64(&w1g[4 * Z + q], m);
        }
      }
    } else if (wv == 1) {
      if (p >= 1) {   // L2 step t=p-1, part 1: B1 = s1(p-1)@W_12.T
        float acc[4] = {0.f, 0.f, 0.f, 0.f};
        chain1024(m1, ldsW[1], lane, acc, fone);
        #pragma unroll
        for (int q = 0; q < 4; ++q) B1[q] = acc[q];
      }
    } else {
      if (p >= 1) {   // L2 part 2: B2 = s2(p-2)@W_h2.T
        float acc[4] = {0.f, 0.f, 0.f, 0.f};
        chain1024(m2, ldsW[2], lane, acc, fone);
        #pragma unroll
        for (int q = 0; q < 4; ++q) xch[q][lane] = acc[q];
      }
    }
    __syncthreads();
    if (wv == 1 && p >= 1) {   // combine + LIF2 + publish (exact R4 op order)
      #pragma unroll
      for (int q = 0; q < 4; ++q) {
        float C = __fadd_rn(B1[q], bA[q]);                        // B1 + b_12
        float h = __fadd_rn(__fadd_rn(C, xch[q][lane]), bh2v[q]); // (C+B2)+b_h2
        v[q] = __fadd_rn(__fmul_rn(0.9f, v[q]), h);
        bool s = (v[q] >= 1.0f);
        if (s) { v[q] = __fsub_rn(v[q], 1.0f); cnt[q]++; }
        uint64_t m = __ballot(s);
        if (lane == 0) st64(&w2g[4 * Z + q], m);
      }
    }
    gridbar(arena, mygen);
  }

  if (wv == 1) {
    #pragma unroll
    for (int q = 0; q < 4; ++q) cnt2[(size_t)lane * kH + 4 * Z + q] = cnt[q];
  }
}

// ---------- exact f64 readout: out[b][o] = sum_j cnt[b][j]*W_out[o][j] + 512*b_out[o] ----------
__global__ void readout(const uint32_t* __restrict__ cnt2, const float* __restrict__ W_out,
                        const float* __restrict__ b_out, float* __restrict__ out) {
  const int b = blockIdx.x;    // 64
  const int o = threadIdx.x;   // 256
  double po = 512.0 * (double)b_out[o];
  for (int j = 0; j < kH; j += 4) {
    uint4  c4 = *(const uint4*)(cnt2 + (size_t)b * kH + j);
    float4 w4 = *(const float4*)(W_out + (size_t)o * kH + j);
    po = fma((double)c4.x, (double)w4.x, po);
    po = fma((double)c4.y, (double)w4.y, po);
    po = fma((double)c4.z, (double)w4.z, po);
    po = fma((double)c4.w, (double)w4.w, po);
  }
  out[(size_t)b * kO + o] = (float)po;
}

extern "C" void kernel_launch(void* const* d_in, const int* in_sizes, int n_in,
                              void* d_out, int out_size, void* d_ws, size_t ws_size,
                              hipStream_t stream) {
  (void)in_sizes; (void)n_in; (void)out_size; (void)ws_size;
  const float* x     = (const float*)d_in[0];
  const float* W_in  = (const float*)d_in[1];
  const float* pb_in = (const float*)d_in[2];
  const float* W_h1  = (const float*)d_in[3];
  const float* pb_h1 = (const float*)d_in[4];
  const float* W_12  = (const float*)d_in[5];
  const float* pb_12 = (const float*)d_in[6];
  const float* W_h2  = (const float*)d_in[7];
  const float* pb_h2 = (const float*)d_in[8];
  const float* W_out = (const float*)d_in[9];
  const float* pb_out= (const float*)d_in[10];
  float* out = (float*)d_out;

  char* ws = (char*)d_ws;
  float*    U2    = (float*)   (ws + OFF_U2);
  float*    WinT  = (float*)   (ws + OFF_WINT);
  float*    Wh1S  = (float*)   (ws + OFF_WS1);
  float*    W12S  = (float*)   (ws + OFF_WS2);
  float*    Wh2S  = (float*)   (ws + OFF_WS3);
  uint64_t* s1r   = (uint64_t*)(ws + OFF_S1R);
  uint64_t* s2r   = (uint64_t*)(ws + OFF_S2R);
  uint32_t* cnt2  = (uint32_t*)(ws + OFF_CNT);
  uint32_t* arena = (uint32_t*)(ws + OFF_BAR);

  hipMemsetAsync(arena, 0, ARN_BYTES, stream);
  hipLaunchKernelGGL(transpose_k, dim3(kD / 32, kH / 32), dim3(32, 8), 0, stream,
                     W_in, WinT, kH, kD);
  hipLaunchKernelGGL(wtr_sl, dim3(kH, 4), dim3(256), 0, stream, W_h1, Wh1S);
  hipLaunchKernelGGL(wtr_sl, dim3(kH, 4), dim3(256), 0, stream, W_12, W12S);
  hipLaunchKernelGGL(wtr_sl, dim3(kH, 4), dim3(256), 0, stream, W_h2, Wh2S);
  hipLaunchKernelGGL(uproj, dim3(kT, 16), dim3(256), 0, stream, x, WinT, pb_in, U2);

  void* args[] = {(void*)&U2, (void*)&Wh1S, (void*)&W12S, (void*)&Wh2S,
                  (void*)&pb_h1, (void*)&pb_12, (void*)&pb_h2,
                  (void*)&s1r, (void*)&s2r, (void*)&cnt2, (void*)&arena};
  hipLaunchCooperativeKernel((void*)snn6, dim3(NBLK), dim3(NTHR), args, 0, stream);

  hipLaunchKernelGGL(readout, dim3(kB), dim3(kO), 0, stream, cnt2, W_out, pb_out, out);
}

// Round 11
// 12840.126 us; speedup vs baseline: 3.2848x; 1.3119x over previous
//
#include <hip/hip_runtime.h>
#include <stdint.h>

// ---------------- problem sizes ----------------
constexpr int kB = 64, kT = 512, kD = 512, kH = 1024, kO = 256;

// ---------------- grid config ----------------
constexpr int NBLK = 256;   // block Z owns units 4Z..4Z+3 of L1 AND L2, all 64 batches
constexpr int NTHR = 192;   // wave 0: L1(Wh1)  wave 1: W12(+LIF2+combine)  wave 2: Wh2

// ---------------- ws layout (bytes) — total ~142.3 MB (== R4's proven footprint) ----------------
constexpr size_t OFF_U2   = 0;                                   // U2[t][b][u] f32 (128 MB) = x@W_in.T + b_in
constexpr size_t OFF_WINT = OFF_U2   + (size_t)kT*kB*kH*4;       // WinT[k][u] f32 (2 MB)
constexpr size_t OFF_WS1  = OFF_WINT + (size_t)kD*kH*4;          // Wh1 sliced [u/4][j][4] (4 MB)
constexpr size_t OFF_WS2  = OFF_WS1  + (size_t)kH*kH*4;          // W12 sliced
constexpr size_t OFF_WS3  = OFF_WS2  + (size_t)kH*kH*4;          // Wh2 sliced
constexpr size_t OFF_S1R  = OFF_WS3  + (size_t)kH*kH*4;          // 2 x 1024 u64 rows (bits=batch)
constexpr size_t OFF_S2R  = OFF_S1R  + 2*kH*8;
constexpr size_t OFF_CNT  = OFF_S2R  + 2*kH*8;                   // cnt[b][u] u32 (256 KB)
constexpr size_t OFF_BAR  = OFF_CNT  + (size_t)kB*kH*4;          // barrier arena (4 KB)

// barrier arena (memset to 0 each launch):
//   arr[8] u32 @ +0, stride 128 B   (per-group arrival counters, 32 serialized RMWs each)
//   top    u32 @ +1024              (8 RMWs per generation)
//   rel    u32 @ +2048              (single release word — R11's proven poll target)
constexpr int    LINE_W    = 32;   // 128 B / 4
constexpr size_t ARN_BYTES = 4096;

// cross-block data via agent-scope atomics (per-XCD L2s not coherent)
__device__ __forceinline__ uint64_t ld64(const uint64_t* p) {
  return __hip_atomic_load(p, __ATOMIC_RELAXED, __HIP_MEMORY_SCOPE_AGENT);
}
__device__ __forceinline__ void st64(uint64_t* p, uint64_t v) {
  __hip_atomic_store(p, v, __ATOMIC_RELAXED, __HIP_MEMORY_SCOPE_AGENT);
}

// R14 grid barrier (proven 12.0 ms): R11's release/poll path (single rel word,
// RELAXED spin, s_sleep, ONE trailing ACQUIRE load = single buffer_inv) + tree
// arrival (arr[Z&7] 8x32 RMWs -> top 8 RMWs -> rel). UNCHANGED this round.
__device__ __forceinline__ void gridbar(uint32_t* arena, uint32_t& mygen) {
  __syncthreads();
  const uint32_t g = mygen + 1;
  if (threadIdx.x == 0) {
    const int x = blockIdx.x & 7;
    uint32_t* arr = arena + x * LINE_W;
    uint32_t* top = arena + (1024 / 4);
    uint32_t* rel = arena + (2048 / 4);
    uint32_t c = __hip_atomic_fetch_add(arr, 1u, __ATOMIC_ACQ_REL, __HIP_MEMORY_SCOPE_AGENT);
    if (c == g * 32u - 1u) {                 // last arrival in this group for gen g
      uint32_t t = __hip_atomic_fetch_add(top, 1u, __ATOMIC_ACQ_REL, __HIP_MEMORY_SCOPE_AGENT);
      if (t == g * 8u - 1u)                  // last group overall for gen g
        __hip_atomic_store(rel, g, __ATOMIC_RELEASE, __HIP_MEMORY_SCOPE_AGENT);
    }
    while (__hip_atomic_load(rel, __ATOMIC_RELAXED, __HIP_MEMORY_SCOPE_AGENT) < g)
      __builtin_amdgcn_s_sleep(1);
    (void)__hip_atomic_load(rel, __ATOMIC_ACQUIRE, __HIP_MEMORY_SCOPE_AGENT);  // single inv
  }
  __syncthreads();
  mygen = g;
}

// ---------- transpose f32 in[R][C] -> out[C][R] (for WinT) ----------
__global__ void transpose_k(const float* __restrict__ in, float* __restrict__ out,
                            int R, int C) {
  __shared__ float tile[32][33];
  int c0 = blockIdx.x * 32, r0 = blockIdx.y * 32;
  int tx = threadIdx.x, ty = threadIdx.y;           // (32,8)
  for (int k = 0; k < 32; k += 8)
    tile[ty + k][tx] = in[(size_t)(r0 + ty + k) * C + c0 + tx];
  __syncthreads();
  for (int k = 0; k < 32; k += 8)
    out[(size_t)(c0 + ty + k) * R + r0 + tx] = tile[tx][ty + k];
}

// ---------- W[1024][1024] -> sliced S[(u>>2)*1024 + j][4] with S[..][q] = W[4Z+q][j] ----------
__global__ void wtr_sl(const float* __restrict__ in, float* __restrict__ out) {
  int u = blockIdx.x;
  int j = blockIdx.y * 256 + threadIdx.x;
  float v = in[(size_t)u * kH + j];
  out[((size_t)(u >> 2) * kH + j) * 4 + (u & 3)] = v;
}

// ---------- U2[t][b][u] = x@W_in.T + b_in ----------
// R15 rewrite: the old kernel's x loads were WAVE-UNIFORM 16B requests (the float4
// address does not depend on lane) — 2048 broadcast LLC/HBM round trips per block,
// 16x re-fetch of x across uc blocks: latency-bound, ~4ms for a 0.3ms job.
// Now: each wave coalesced-stages its own 16 batches x 256 k into LDS (64 KB/block,
// 2 phases over k), then reads via LDS broadcast. The per-output accumulation is
// UNCHANGED: ascending k, single chain, same fma order -> U2 bit-identical.
__global__ __launch_bounds__(256) void uproj(const float* __restrict__ x,
                                             const float* __restrict__ WinT,
                                             const float* __restrict__ b_in,
                                             float* __restrict__ U2) {
  __shared__ float xs[64][256];                // 64 KB: x[b][t][kbase..kbase+255]
  const int t    = blockIdx.x;                 // 512
  const int uc   = blockIdx.y;                 // 16
  const int lane = threadIdx.x & 63;
  const int wvu  = __builtin_amdgcn_readfirstlane(threadIdx.x >> 6);  // 0..3
  const int u    = uc * 64 + lane;
  const int b0   = wvu * 16;
  float acc[16];
  #pragma unroll
  for (int i = 0; i < 16; ++i) acc[i] = 0.0f;

  for (int ph = 0; ph < 2; ++ph) {
    const int kbase = ph * 256;
    // stage: wave wvu loads its own 16 batch-rows, 256 k each; lane l takes float4
    // chunk l of each row -> 1 KB coalesced per instruction, 16 independent loads.
    #pragma unroll
    for (int bb = 0; bb < 16; ++bb) {
      const float* src = x + ((size_t)(b0 + bb) * kT + t) * kD + kbase;
      *(float4*)&xs[b0 + bb][lane * 4] = *(const float4*)(src + lane * 4);
    }
    __syncthreads();   // LDS visible (also orders ph1 overwrite after ph0 reads)
    for (int kk = 0; kk < 256; kk += 4) {
      const int k = kbase + kk;
      float w0 = WinT[(size_t)(k + 0) * kH + u];
      float w1 = WinT[(size_t)(k + 1) * kH + u];
      float w2 = WinT[(size_t)(k + 2) * kH + u];
      float w3 = WinT[(size_t)(k + 3) * kH + u];
      #pragma unroll
      for (int bb = 0; bb < 16; ++bb) {
        const float4 xv = *(const float4*)&xs[b0 + bb][kk];   // LDS broadcast read
        acc[bb] = __fmaf_rn(xv.x, w0, acc[bb]);   // ascending k, single chain: np-exact
        acc[bb] = __fmaf_rn(xv.y, w1, acc[bb]);
        acc[bb] = __fmaf_rn(xv.z, w2, acc[bb]);
        acc[bb] = __fmaf_rn(xv.w, w3, acc[bb]);
      }
    }
    __syncthreads();   // all reads of this phase done before restage
  }

  float bi = b_in[u];
  #pragma unroll
  for (int bb = 0; bb < 16; ++bb)
    U2[((size_t)t * kB + (b0 + bb)) * kH + u] = __fadd_rn(acc[bb], bi);
}

// sequential-j chain over 1024 spike-gated weights from LDS; bit-exact vs R4:
// fma(w, sf, B) with sf in {0,1} == fadd(B, bit?w:0); B starts +0 and RN cancellation
// yields +0, so B is never -0 and the ±0 corners coincide.
// `rows` points to the LDS-staged mask copy (R10); readlane values per (g,lane)
// identical -> bit-exact.
__device__ __forceinline__ void chain1024(const uint64_t* rows, const float4* wlds,
                                          int lane, float acc[4], float fone) {
  float4 bufA[8], bufB[8];                              // static-indexed only (no scratch)
  uint64_t cur = rows[lane];                            // group 0: lane L holds word j=L
  #pragma unroll
  for (int i = 0; i < 8; ++i) bufA[i] = wlds[i];        // preload j=0..7
  #pragma unroll 1
  for (int g = 0; g < 16; ++g) {
    uint64_t nxt = (g < 15) ? rows[(g + 1) * 64 + lane] : 0ull;  // prefetch next group
    uint32_t lo = (uint32_t)cur, hi = (uint32_t)(cur >> 32);
    const float4* wg = wlds + g * 64;
    #pragma unroll
    for (int sb = 0; sb < 8; ++sb) {                    // 8 sub-blocks of 8 jj
      // issue prefetch of sub-block sb+1 into the other buffer (8x ds_read_b128)
      #pragma unroll
      for (int i = 0; i < 8; ++i) {
        float4 w = wg[(sb + 1) * 8 + i];                // sb=7,g=15 -> pad region (unused)
        if (sb & 1) bufA[i] = w; else bufB[i] = w;
      }
      // consume sub-block sb
      #pragma unroll
      for (int i = 0; i < 8; ++i) {
        const int jj = sb * 8 + i;
        uint32_t rlo = (uint32_t)__builtin_amdgcn_readlane((int)lo, jj);  // word for j=g*64+jj
        uint32_t rhi = (uint32_t)__builtin_amdgcn_readlane((int)hi, jj);
        uint64_t rw  = ((uint64_t)rhi << 32) | rlo;     // uniform -> SGPR pair
        float sf;
        asm("v_cndmask_b32 %0, 0, %1, %2" : "=v"(sf) : "v"(fone), "s"(rw));  // sf = bit(lane)
        float4 w4 = (sb & 1) ? bufB[i] : bufA[i];       // compile-time select
        acc[0] = __fmaf_rn(w4.x, sf, acc[0]);
        acc[1] = __fmaf_rn(w4.y, sf, acc[1]);
        acc[2] = __fmaf_rn(w4.z, sf, acc[2]);
        acc[3] = __fmaf_rn(w4.w, sf, acc[3]);
      }
    }
    cur = nxt;
  }
}

// ---------- persistent SNN: lanes = batch, block Z owns units 4Z..4Z+3, weights LDS-resident ----------
// Masks staged global->LDS per step, all loads back-to-back (R10, pipelined at LLC).
// UNCHANGED from R14 (proven 12.0 ms steady).
__global__ __launch_bounds__(NTHR, 1) void snn6(
    const float* __restrict__ U2,
    const float* __restrict__ Wh1S, const float* __restrict__ W12S,
    const float* __restrict__ Wh2S,
    const float* __restrict__ b_h1, const float* __restrict__ b_12,
    const float* __restrict__ b_h2,
    uint64_t* s1rows, uint64_t* s2rows, uint32_t* cnt2, uint32_t* arena)
{
  __shared__ float4 ldsW[3][kH + 8];   // ~48.4 KB: per-role 4-unit weight slice + prefetch pad
  __shared__ float  xch[4][64];        // B2 exchange (Wh2 wave -> W12 wave)
  __shared__ uint64_t m1[kH];          // 8 KB: staged s1 gen p-1 masks
  __shared__ uint64_t m2[kH];          // 8 KB: staged s2 gen p-2 masks

  const int tid  = threadIdx.x;
  const int lane = tid & 63;                                          // batch
  const int wv   = __builtin_amdgcn_readfirstlane(tid >> 6);          // role 0/1/2
  const int Z    = blockIdx.x;
  uint32_t mygen = 0;
  const float fone = 1.0f;

  // ---- one-time: preload this role's 16 KB weight slice into LDS (coalesced)
  {
    const float* Wsrc = (wv == 0) ? Wh1S : (wv == 1) ? W12S : Wh2S;
    const float4* gs = (const float4*)Wsrc + (size_t)Z * kH;
    #pragma unroll
    for (int i = 0; i < 16; ++i) {
      int idx = i * 64 + lane;
      ldsW[wv][idx] = gs[idx];
    }
  }

  // ---- zero both generations of both spike-row buffers
  {
    int idx = Z * NTHR + tid;
    if (idx < 2 * kH) { st64(&s1rows[idx], 0ull); st64(&s2rows[idx], 0ull); }
  }
  gridbar(arena, mygen);   // also makes LDS preload visible block-wide

  float bA[4];           // role bias: b_h1 / b_12 / b_h2 for units 4Z..4Z+3
  float bh2v[4];         // W12 wave also needs b_h2 for the combine
  float v[4];            // membrane state per (unit q, batch lane)
  float B1[4];           // W12 wave: stashed partial across syncthreads
  uint32_t cnt[4] = {0, 0, 0, 0};
  #pragma unroll
  for (int q = 0; q < 4; ++q) {
    v[q] = 0.0f;
    B1[q] = 0.0f;
    bA[q]   = (wv == 0) ? b_h1[4 * Z + q] : (wv == 1) ? b_12[4 * Z + q] : b_h2[4 * Z + q];
    bh2v[q] = b_h2[4 * Z + q];
  }

  for (int p = 0; p <= kT; ++p) {
    const uint64_t* r1g = s1rows + ((p & 1) ^ 1) * kH;   // s1 gen p-1
    uint64_t*       w1g = s1rows + (p & 1) * kH;         // s1 gen p
    const uint64_t* r2g = s2rows + (p & 1) * kH;         // s2 gen p-2
    uint64_t*       w2g = s2rows + ((p & 1) ^ 1) * kH;   // s2 gen p-1

    // ---- stage masks global->LDS, all loads issued before any LDS write
    if (wv == 0) {
      uint64_t t0[8];
      #pragma unroll
      for (int g = 0; g < 8; ++g) t0[g] = ld64(&r1g[g * 64 + lane]);
      #pragma unroll
      for (int g = 0; g < 8; ++g) m1[g * 64 + lane] = t0[g];
    } else if (wv == 1) {
      uint64_t t0[8];
      #pragma unroll
      for (int g = 0; g < 8; ++g) t0[g] = ld64(&r1g[(8 + g) * 64 + lane]);
      #pragma unroll
      for (int g = 0; g < 8; ++g) m1[(8 + g) * 64 + lane] = t0[g];
    } else {
      uint64_t t0[16];
      #pragma unroll
      for (int g = 0; g < 16; ++g) t0[g] = ld64(&r2g[g * 64 + lane]);
      #pragma unroll
      for (int g = 0; g < 16; ++g) m2[g * 64 + lane] = t0[g];
    }
    __syncthreads();   // staged masks visible block-wide

    if (wv == 0) {
      if (p < kT) {   // L1 step t=p
        // prefetch A early (no deps on the chain): latency hidden by chain1024
        float4 A4 = *(const float4*)(U2 + ((size_t)p * kB + lane) * kH + 4 * Z);
        float acc[4] = {0.f, 0.f, 0.f, 0.f};
        chain1024(m1, ldsW[0], lane, acc, fone);                 // s1(p-1)@W_h1.T
        float A[4] = {A4.x, A4.y, A4.z, A4.w};
        #pragma unroll
        for (int q = 0; q < 4; ++q) {
          float h = __fadd_rn(__fadd_rn(A[q], acc[q]), bA[q]);   // ((x@W+b_in)+rec)+b_h1
          v[q] = __fadd_rn(__fmul_rn(0.9f, v[q]), h);
          bool s = (v[q] >= 1.0f);
          if (s) v[q] = __fsub_rn(v[q], 1.0f);
          uint64_t m = __ballot(s);                              // bits = batches
          if (lane == 0) st64(&w1g[4 * Z + q], m);
        }
      }
    } else if (wv == 1) {
      if (p >= 1) {   // L2 step t=p-1, part 1: B1 = s1(p-1)@W_12.T
        float acc[4] = {0.f, 0.f, 0.f, 0.f};
        chain1024(m1, ldsW[1], lane, acc, fone);
        #pragma unroll
        for (int q = 0; q < 4; ++q) B1[q] = acc[q];
      }
    } else {
      if (p >= 1) {   // L2 part 2: B2 = s2(p-2)@W_h2.T
        float acc[4] = {0.f, 0.f, 0.f, 0.f};
        chain1024(m2, ldsW[2], lane, acc, fone);
        #pragma unroll
        for (int q = 0; q < 4; ++q) xch[q][lane] = acc[q];
      }
    }
    __syncthreads();
    if (wv == 1 && p >= 1) {   // combine + LIF2 + publish (exact R4 op order)
      #pragma unroll
      for (int q = 0; q < 4; ++q) {
        float C = __fadd_rn(B1[q], bA[q]);                        // B1 + b_12
        float h = __fadd_rn(__fadd_rn(C, xch[q][lane]), bh2v[q]); // (C+B2)+b_h2
        v[q] = __fadd_rn(__fmul_rn(0.9f, v[q]), h);
        bool s = (v[q] >= 1.0f);
        if (s) { v[q] = __fsub_rn(v[q], 1.0f); cnt[q]++; }
        uint64_t m = __ballot(s);
        if (lane == 0) st64(&w2g[4 * Z + q], m);
      }
    }
    gridbar(arena, mygen);
  }

  if (wv == 1) {
    #pragma unroll
    for (int q = 0; q < 4; ++q) cnt2[(size_t)lane * kH + 4 * Z + q] = cnt[q];
  }
}

// ---------- exact f64 readout: out[b][o] = sum_j cnt[b][j]*W_out[o][j] + 512*b_out[o] ----------
__global__ void readout(const uint32_t* __restrict__ cnt2, const float* __restrict__ W_out,
                        const float* __restrict__ b_out, float* __restrict__ out) {
  const int b = blockIdx.x;    // 64
  const int o = threadIdx.x;   // 256
  double po = 512.0 * (double)b_out[o];
  for (int j = 0; j < kH; j += 4) {
    uint4  c4 = *(const uint4*)(cnt2 + (size_t)b * kH + j);
    float4 w4 = *(const float4*)(W_out + (size_t)o * kH + j);
    po = fma((double)c4.x, (double)w4.x, po);
    po = fma((double)c4.y, (double)w4.y, po);
    po = fma((double)c4.z, (double)w4.z, po);
    po = fma((double)c4.w, (double)w4.w, po);
  }
  out[(size_t)b * kO + o] = (float)po;
}

extern "C" void kernel_launch(void* const* d_in, const int* in_sizes, int n_in,
                              void* d_out, int out_size, void* d_ws, size_t ws_size,
                              hipStream_t stream) {
  (void)in_sizes; (void)n_in; (void)out_size; (void)ws_size;
  const float* x     = (const float*)d_in[0];
  const float* W_in  = (const float*)d_in[1];
  const float* pb_in = (const float*)d_in[2];
  const float* W_h1  = (const float*)d_in[3];
  const float* pb_h1 = (const float*)d_in[4];
  const float* W_12  = (const float*)d_in[5];
  const float* pb_12 = (const float*)d_in[6];
  const float* W_h2  = (const float*)d_in[7];
  const float* pb_h2 = (const float*)d_in[8];
  const float* W_out = (const float*)d_in[9];
  const float* pb_out= (const float*)d_in[10];
  float* out = (float*)d_out;

  char* ws = (char*)d_ws;
  float*    U2    = (float*)   (ws + OFF_U2);
  float*    WinT  = (float*)   (ws + OFF_WINT);
  float*    Wh1S  = (float*)   (ws + OFF_WS1);
  float*    W12S  = (float*)   (ws + OFF_WS2);
  float*    Wh2S  = (float*)   (ws + OFF_WS3);
  uint64_t* s1r   = (uint64_t*)(ws + OFF_S1R);
  uint64_t* s2r   = (uint64_t*)(ws + OFF_S2R);
  uint32_t* cnt2  = (uint32_t*)(ws + OFF_CNT);
  uint32_t* arena = (uint32_t*)(ws + OFF_BAR);

  hipMemsetAsync(arena, 0, ARN_BYTES, stream);
  hipLaunchKernelGGL(transpose_k, dim3(kD / 32, kH / 32), dim3(32, 8), 0, stream,
                     W_in, WinT, kH, kD);
  hipLaunchKernelGGL(wtr_sl, dim3(kH, 4), dim3(256), 0, stream, W_h1, Wh1S);
  hipLaunchKernelGGL(wtr_sl, dim3(kH, 4), dim3(256), 0, stream, W_12, W12S);
  hipLaunchKernelGGL(wtr_sl, dim3(kH, 4), dim3(256), 0, stream, W_h2, Wh2S);
  hipLaunchKernelGGL(uproj, dim3(kT, 16), dim3(256), 0, stream, x, WinT, pb_in, U2);

  void* args[] = {(void*)&U2, (void*)&Wh1S, (void*)&W12S, (void*)&Wh2S,
                  (void*)&pb_h1, (void*)&pb_12, (void*)&pb_h2,
                  (void*)&s1r, (void*)&s2r, (void*)&cnt2, (void*)&arena};
  hipLaunchCooperativeKernel((void*)snn6, dim3(NBLK), dim3(NTHR), args, 0, stream);

  hipLaunchKernelGGL(readout, dim3(kB), dim3(kO), 0, stream, cnt2, W_out, pb_out, out);
}